// Round 5
// baseline (1753.292 us; speedup 1.0000x reference)
//
#include <hip/hip_runtime.h>

// Problem constants
#define B_   16
#define T_   16
#define H_   161
#define W_   181
#define HW_  (H_*W_)     // 29141
#define C_   3
#define F_   21
#define F4_  84
#define TSX  32          // tile width
#define TSY  8           // tile height (256 px per block)
#define TPX  34          // tile + halo
#define TPY  10
#define NPOS (TPX*TPY)   // 340
#define NTAP 9
#define MT_  6           // m-tiles of 16 -> 96 gate rows (m = f*4+gate)
#define NT_  4           // n-tiles of 16 px per wave-row-group
#define ROWB 128         // LDS bytes per position: 8 slots x 16B (4 k-groups x {hi,lo})
// ci map: 0..20 = h channels (recurrent), 21..23 = zero pad, 24..26 = x, 27..31 = zero pad
#define GH_LO ((size_t)B_ * 3 * HW_)   // uint4 elements per plane (hi or lo) = 1,398,768

typedef short bf16x8 __attribute__((ext_vector_type(8)));
typedef float f32x4  __attribute__((ext_vector_type(4)));

__device__ __forceinline__ float hsig(float x) {
  return fminf(fmaxf(0.2f * x + 0.5f, 0.0f), 1.0f);
}

__device__ __forceinline__ float fast_tanh(float x) {
  float ax = fabsf(x);
  float t = __expf(-2.0f * ax);
  float r = (1.0f - t) * __builtin_amdgcn_rcpf(1.0f + t);
  return copysignf(r, x);
}

// round-to-nearest-even fp32 -> bf16 bits
__device__ __forceinline__ unsigned short bf16r(float x) {
  unsigned u = __float_as_uint(x);
  return (unsigned short)((u + 0x7FFFu + ((u >> 16) & 1u)) >> 16);
}
__device__ __forceinline__ void bsplit(float v, unsigned short& hi, unsigned short& lo) {
  hi = bf16r(v);
  float hf = __uint_as_float((unsigned)hi << 16);
  lo = bf16r(v - hf);
}

// A-fragment pack: Af[tap][mt][hl][lane] (uint4 = 8 bf16).
// mfma_f32_16x16x32_bf16 A layout (HW-verified round 2): row m = lane&15,
// k = (lane>>4)*8 + j. m = f*4 + gate; oc = gate*21 + f (Keras i,f,c,o).
__global__ void prep_kernel(const float* __restrict__ k,
                            const float* __restrict__ rk,
                            const float* __restrict__ bias,
                            unsigned short* __restrict__ Af,
                            float* __restrict__ bias4) {
  int i = blockIdx.x * 256 + threadIdx.x;
  if (i < NTAP * MT_ * 2 * 64 * 8) {
    int j    = i & 7;
    int lane = (i >> 3) & 63;
    int hl   = (i >> 9) & 1;
    int mtp  = i >> 10;          // tap*MT_ + mt
    int mt   = mtp % MT_;
    int tap  = mtp / MT_;
    int m    = mt * 16 + (lane & 15);
    int ci   = (lane >> 4) * 8 + j;
    int f    = m >> 2, gate = m & 3;
    float w = 0.0f;
    if (f < F_) {
      int oc = gate * F_ + f;
      if (ci < F_)                  w = rk[(tap * F_ + ci) * F4_ + oc];        // h channels
      else if (ci >= 24 && ci < 27) w = k[(tap * C_ + (ci - 24)) * F4_ + oc];  // x channels
    }
    unsigned short hb = bf16r(w);
    unsigned short outv;
    if (hl == 0) outv = hb;
    else {
      float hf = __uint_as_float((unsigned)hb << 16);
      outv = bf16r(w - hf);
    }
    Af[i] = outv;
  }
  if (i < 96) {   // bias4[f][gate], f padded to 24
    int f = i >> 2, gate = i & 3;
    bias4[i] = (f < F_) ? bias[gate * F_ + f] : 0.0f;
  }
}

// ---------------- packed-h path (needs ~129 MB ws) ----------------
// grid (6,21,16), block 512 (8 waves). wv>>1 = pixel-row pair (0..3),
// wv&1 = m-half (3 m-tiles each) -> acc 3x4 f32x4 = 48 regs/wave.
// h exchanged between steps as pre-split bf16 hi/lo in MFMA slot layout
// (ghA/ghB double buffer): staging is pure 16B copies, conflict-free.
// Round 5: c_buf prefetched into regs right after the barrier (overlaps MFMA
// phase instead of trailing it); s_setprio(1) around the MFMA cluster.
__global__ void __launch_bounds__(512, 4) step_kernel_p(
    const float* __restrict__ x,        // (B,T,H,W,C) fp32
    const uint4* __restrict__ Af,       // [9][6][2][64] uint4
    const float* __restrict__ bias4,    // [24][4]
    const uint4* __restrict__ g_in,     // h bf16 hi/lo planes (prev step)
    uint4* __restrict__ g_out,          // h bf16 hi/lo planes (this step)
    float* __restrict__ c_buf,          // (B,21,HW) fp32 in-place
    const float* __restrict__ mask,     // (H,W,1)
    float* __restrict__ out,            // (B,H,W,21) fp32, last step only
    int t, int first, int last) {
  __shared__ uint4 tileQ[NPOS * 8];     // 43520 B
  unsigned char* tile = (unsigned char*)tileQ;
  unsigned short* bh16 = (unsigned short*)tileQ;   // epilogue bounce hi: [256][24]
  unsigned short* bl16 = bh16 + 256 * 24;          // bounce lo (offset 12288 B)

  int b   = blockIdx.z;
  int by0 = blockIdx.y * TSY;
  int bx0 = blockIdx.x * TSX;
  int tid = threadIdx.x;

  // ---- stage tile: h groups are raw 16B copies; x converted on the fly ----
  for (int i = tid; i < 6 * NPOS + NPOS; i += 512) {
    if (i < 6 * NPOS) {
      int slot = i / NPOS;              // g*2+hl, g=0..2 (h), hl in {0,1}
      int pos  = i - slot * NPOS;
      int g  = slot >> 1, hl = slot & 1;
      int py = pos / TPX, px = pos - py * TPX;
      int gy = by0 - 1 + py, gx = bx0 - 1 + px;
      uint4 v = {0u, 0u, 0u, 0u};
      if (!first && (unsigned)gy < (unsigned)H_ && (unsigned)gx < (unsigned)W_) {
        v = g_in[(size_t)hl * GH_LO + (size_t)(b * 3 + g) * HW_ + gy * W_ + gx];
      }
      *(uint4*)&tile[pos * ROWB + ((slot ^ (pos & 7)) * 16)] = v;
    } else {
      int pos = i - 6 * NPOS;
      int py = pos / TPX, px = pos - py * TPX;
      int gy = by0 - 1 + py, gx = bx0 - 1 + px;
      float x0 = 0.f, x1 = 0.f, x2 = 0.f;
      if ((unsigned)gy < (unsigned)H_ && (unsigned)gx < (unsigned)W_) {
        const float* xp = x + (((size_t)(b * T_ + t) * H_ + gy) * W_ + gx) * C_;
        x0 = xp[0]; x1 = xp[1]; x2 = xp[2];
      }
      unsigned short h0, h1, h2, l0, l1, l2;
      bsplit(x0, h0, l0); bsplit(x1, h1, l1); bsplit(x2, h2, l2);
      uint4 vh = {(unsigned)h0 | ((unsigned)h1 << 16), (unsigned)h2, 0u, 0u};
      uint4 vl = {(unsigned)l0 | ((unsigned)l1 << 16), (unsigned)l2, 0u, 0u};
      int sw = pos & 7;
      *(uint4*)&tile[pos * ROWB + ((6 ^ sw) * 16)] = vh;
      *(uint4*)&tile[pos * ROWB + ((7 ^ sw) * 16)] = vl;
    }
  }
  __syncthreads();

  int lane = tid & 63;
  int wv   = tid >> 6;     // 0..7
  int wvn  = wv >> 1;      // pixel-row pair 0..3
  int wvm  = wv & 1;       // m-half 0..1
  int ln15 = lane & 15;
  int lg   = lane >> 4;

  // ---- c prefetch: issue AFTER the barrier so the loads overlap the MFMA
  // phase (compiler drains vmcnt at barriers, so issuing before would stall).
  float cpre[3][NT_];
#pragma unroll
  for (int mt = 0; mt < 3; ++mt) {
    int f = (wvm * 3 + mt) * 4 + lg;
#pragma unroll
    for (int nt = 0; nt < NT_; ++nt) {
      int gy = by0 + wvn * 2 + (nt >> 1);
      int gx = bx0 + (nt & 1) * 16 + ln15;
      float cv = 0.0f;
      if (!first && f < F_ && gy < H_ && gx < W_)
        cv = c_buf[((size_t)b * F_ + f) * HW_ + (size_t)gy * W_ + gx];
      cpre[mt][nt] = cv;
    }
  }

  f32x4 acc[3][NT_];
#pragma unroll
  for (int mt = 0; mt < 3; ++mt)
#pragma unroll
    for (int nt = 0; nt < NT_; ++nt)
      acc[mt][nt] = (f32x4){0.f, 0.f, 0.f, 0.f};

#pragma unroll 1
  for (int tap = 0; tap < NTAP; ++tap) {
    int ky = tap / 3;
    int kx = tap - 3 * ky;

    bf16x8 bh[NT_], bl[NT_];
#pragma unroll
    for (int nt = 0; nt < NT_; ++nt) {
      int pos = (wvn * 2 + (nt >> 1) + ky) * TPX + (nt & 1) * 16 + ln15 + kx;
      int sw  = pos & 7;
      uint4 hv = *(const uint4*)&tile[pos * ROWB + (((lg * 2 + 0) ^ sw) * 16)];
      uint4 lv = *(const uint4*)&tile[pos * ROWB + (((lg * 2 + 1) ^ sw) * 16)];
      bh[nt] = __builtin_bit_cast(bf16x8, hv);
      bl[nt] = __builtin_bit_cast(bf16x8, lv);
    }

    __builtin_amdgcn_s_setprio(1);
#pragma unroll
    for (int mt = 0; mt < 3; ++mt) {
      const uint4* ap = Af + (size_t)((tap * MT_ + (wvm * 3 + mt)) * 2) * 64 + lane;
      bf16x8 ah = __builtin_bit_cast(bf16x8, ap[0]);
      bf16x8 al = __builtin_bit_cast(bf16x8, ap[64]);
#pragma unroll
      for (int nt = 0; nt < NT_; ++nt) {
        acc[mt][nt] = __builtin_amdgcn_mfma_f32_16x16x32_bf16(ah, bh[nt], acc[mt][nt], 0, 0, 0);
        acc[mt][nt] = __builtin_amdgcn_mfma_f32_16x16x32_bf16(ah, bl[nt], acc[mt][nt], 0, 0, 0);
        acc[mt][nt] = __builtin_amdgcn_mfma_f32_16x16x32_bf16(al, bh[nt], acc[mt][nt], 0, 0, 0);
      }
    }
    __builtin_amdgcn_s_setprio(0);
  }

  __syncthreads();   // tile consumed; reuse LDS as epilogue bounce

  // ---- lane-local LSTM epilogue; h -> bounce LDS as split bf16 ----
#pragma unroll
  for (int mt = 0; mt < 3; ++mt) {
    int f = (wvm * 3 + mt) * 4 + lg;    // 0..23 (21..23 -> exact zero h)
    float4 bb = ((const float4*)bias4)[f];
#pragma unroll
    for (int nt = 0; nt < NT_; ++nt) {
      int py = wvn * 2 + (nt >> 1);
      int px = (nt & 1) * 16 + ln15;
      int gy = by0 + py, gx = bx0 + px;
      if (gy < H_ && gx < W_) {
        int    pixL = py * TSX + px;
        size_t gpix = (size_t)gy * W_ + gx;
        float zi = acc[mt][nt][0] + bb.x;
        float zf = acc[mt][nt][1] + bb.y;
        float zc = acc[mt][nt][2] + bb.z;
        float zo = acc[mt][nt][3] + bb.w;
        float ig = hsig(zi);
        float fg = hsig(zf);
        float gg = fast_tanh(zc);
        float og = hsig(zo);
        float cp = cpre[mt][nt];
        float cn = fg * cp + ig * gg;
        float hn = og * fast_tanh(cn);
        if (f < F_ && !last) c_buf[((size_t)b * F_ + f) * HW_ + gpix] = cn;
        if (last) {
          if (f < F_)
            out[((size_t)(b * H_ + gy) * W_ + gx) * F_ + f] = hn * mask[gpix];
        } else {
          unsigned short hh, hlw;
          bsplit(hn, hh, hlw);
          bh16[pixL * 24 + f] = hh;
          bl16[pixL * 24 + f] = hlw;
        }
      }
    }
  }

  if (last) return;
  __syncthreads();

  // ---- pack bounce -> g_out (coalesced 16B stores) ----
  for (int i = tid; i < 256 * 3 * 2; i += 512) {
    int hl   = (i >= 768) ? 1 : 0;
    int j    = i - hl * 768;
    int g    = j >> 8;
    int pixL = j & 255;
    int py = pixL >> 5, px = pixL & 31;
    int gy = by0 + py, gx = bx0 + px;
    if (gy < H_ && gx < W_) {
      const unsigned short* src = (hl ? bl16 : bh16) + pixL * 24 + g * 8;
      uint4 v = *(const uint4*)src;
      g_out[(size_t)hl * GH_LO + (size_t)(b * 3 + g) * HW_ + (size_t)gy * W_ + gx] = v;
    }
  }
}

// ---------------- fallback path (round-2 proven kernel, new ci map, ~78 MB ws) ----
__global__ void __launch_bounds__(256, 3) step_kernel_f(
    const float* __restrict__ x,
    const uint4* __restrict__ Af,
    const float* __restrict__ bias4,
    const float* __restrict__ h_in,     // (B,F,HW) fp32
    float* __restrict__ h_out,          // (B,F,HW) fp32
    float* __restrict__ c_buf,
    const float* __restrict__ mask,
    float* __restrict__ out,
    int t, int first, int last) {
  __shared__ uint4 tileQ[NPOS * 8];
  unsigned char* tile = (unsigned char*)tileQ;

  int b   = blockIdx.z;
  int by0 = blockIdx.y * TSY;
  int bx0 = blockIdx.x * TSX;
  int tid = threadIdx.x;

  for (int i = tid; i < 32 * NPOS; i += 256) {
    int ci  = i / NPOS;
    int pos = i - ci * NPOS;
    int py = pos / TPX, px = pos - py * TPX;
    int gy = by0 - 1 + py, gx = bx0 - 1 + px;
    float v = 0.0f;
    if ((unsigned)gy < (unsigned)H_ && (unsigned)gx < (unsigned)W_) {
      if (ci < F_) {
        if (!first) v = h_in[(size_t)(b * F_ + ci) * HW_ + gy * W_ + gx];
      } else if (ci >= 24 && ci < 27) {
        v = x[(((size_t)(b * T_ + t) * H_ + gy) * W_ + gx) * C_ + (ci - 24)];
      }
    }
    unsigned short hb, lb;
    bsplit(v, hb, lb);
    int g  = ci >> 3, e = ci & 7, sw = pos & 7;
    *(unsigned short*)&tile[pos * ROWB + (((g * 2 + 0) ^ sw) * 16) + e * 2] = hb;
    *(unsigned short*)&tile[pos * ROWB + (((g * 2 + 1) ^ sw) * 16) + e * 2] = lb;
  }
  __syncthreads();

  int lane = tid & 63;
  int wv   = tid >> 6;    // 0..3 -> pixel-row pair
  int ln15 = lane & 15;
  int lg   = lane >> 4;

  f32x4 acc[MT_][NT_];
#pragma unroll
  for (int mt = 0; mt < MT_; ++mt)
#pragma unroll
    for (int nt = 0; nt < NT_; ++nt)
      acc[mt][nt] = (f32x4){0.f, 0.f, 0.f, 0.f};

#pragma unroll 1
  for (int tap = 0; tap < NTAP; ++tap) {
    int ky = tap / 3;
    int kx = tap - 3 * ky;

    bf16x8 bh[NT_], bl[NT_];
#pragma unroll
    for (int nt = 0; nt < NT_; ++nt) {
      int pos = (wv * 2 + (nt >> 1) + ky) * TPX + (nt & 1) * 16 + ln15 + kx;
      int sw  = pos & 7;
      uint4 hv = *(const uint4*)&tile[pos * ROWB + (((lg * 2 + 0) ^ sw) * 16)];
      uint4 lv = *(const uint4*)&tile[pos * ROWB + (((lg * 2 + 1) ^ sw) * 16)];
      bh[nt] = __builtin_bit_cast(bf16x8, hv);
      bl[nt] = __builtin_bit_cast(bf16x8, lv);
    }

#pragma unroll
    for (int mt = 0; mt < MT_; ++mt) {
      const uint4* ap = Af + (size_t)((tap * MT_ + mt) * 2) * 64 + lane;
      bf16x8 ah = __builtin_bit_cast(bf16x8, ap[0]);
      bf16x8 al = __builtin_bit_cast(bf16x8, ap[64]);
#pragma unroll
      for (int nt = 0; nt < NT_; ++nt) {
        acc[mt][nt] = __builtin_amdgcn_mfma_f32_16x16x32_bf16(ah, bh[nt], acc[mt][nt], 0, 0, 0);
        acc[mt][nt] = __builtin_amdgcn_mfma_f32_16x16x32_bf16(ah, bl[nt], acc[mt][nt], 0, 0, 0);
        acc[mt][nt] = __builtin_amdgcn_mfma_f32_16x16x32_bf16(al, bh[nt], acc[mt][nt], 0, 0, 0);
      }
    }
  }

#pragma unroll
  for (int mt = 0; mt < MT_; ++mt) {
    int f = mt * 4 + lg;
    if (f < F_) {
      float4 bb = ((const float4*)bias4)[f];
#pragma unroll
      for (int nt = 0; nt < NT_; ++nt) {
        int gy = by0 + wv * 2 + (nt >> 1);
        int gx = bx0 + (nt & 1) * 16 + ln15;
        if (gy < H_ && gx < W_) {
          size_t idx = ((size_t)b * F_ + f) * HW_ + (size_t)gy * W_ + gx;
          float zi = acc[mt][nt][0] + bb.x;
          float zf = acc[mt][nt][1] + bb.y;
          float zc = acc[mt][nt][2] + bb.z;
          float zo = acc[mt][nt][3] + bb.w;
          float ig = hsig(zi);
          float fg = hsig(zf);
          float gg = fast_tanh(zc);
          float og = hsig(zo);
          float cp = first ? 0.0f : c_buf[idx];
          float cn = fg * cp + ig * gg;
          float hn = og * fast_tanh(cn);
          c_buf[idx] = cn;
          if (!last) h_out[idx] = hn;
          else {
            out[((size_t)(b * H_ + gy) * W_ + gx) * F_ + f] =
                hn * mask[(size_t)gy * W_ + gx];
          }
        }
      }
    }
  }
}

extern "C" void kernel_launch(void* const* d_in, const int* in_sizes, int n_in,
                              void* d_out, int out_size, void* d_ws, size_t ws_size,
                              hipStream_t stream) {
  const float* x  = (const float*)d_in[0];
  const float* k  = (const float*)d_in[1];
  const float* rk = (const float*)d_in[2];
  const float* bs = (const float*)d_in[3];
  const float* mk = (const float*)d_in[4];
  float* outF = (float*)d_out;

  char* ws = (char*)d_ws;
  unsigned short* Af = (unsigned short*)ws;          // 55296 ushort = 110592 B
  float* bias4 = (float*)(ws + 110592);              // 384 B
  size_t off = (size_t)((110592 + 384 + 255) & ~255);  // 111104
  size_t HWF = (size_t)B_ * H_ * W_ * F_;            // 9,791,376

  prep_kernel<<<dim3((NTAP * MT_ * 2 * 64 * 8 + 255) / 256), 256, 0, stream>>>(
      k, rk, bs, Af, bias4);

  dim3 grid((W_ + TSX - 1) / TSX, (H_ + TSY - 1) / TSY, B_);  // (6, 21, 16)

  size_t need_packed = off + (size_t)4 * GH_LO * 16 + HWF * 4;  // ~128.8 MB

  if (ws_size >= need_packed) {
    // packed-h path: ghA/ghB = split-bf16 h planes, c fp32
    uint4* ghA = (uint4*)(ws + off);
    uint4* ghB = ghA + 2 * GH_LO;
    float* cB  = (float*)(ghB + 2 * GH_LO);
    for (int t = 0; t < T_; ++t) {
      const uint4* gin = (t & 1) ? ghB : ghA;
      uint4* gout      = (t & 1) ? ghA : ghB;
      step_kernel_p<<<grid, 512, 0, stream>>>(x, (const uint4*)Af, bias4, gin, gout,
                                              cB, mk, outF, t,
                                              (t == 0) ? 1 : 0, (t == T_ - 1) ? 1 : 0);
    }
  } else {
    // fallback (round-2 proven): fp32 h ping-pong via ws + outF, ~78.4 MB
    float* hA = (float*)(ws + off);
    float* cB = hA + HWF;
    for (int t = 0; t < T_; ++t) {
      const float* hi = (t & 1) ? hA : outF;
      float* ho       = (t & 1) ? outF : hA;
      step_kernel_f<<<grid, 256, 0, stream>>>(x, (const uint4*)Af, bias4, hi, ho,
                                              cB, mk, outF, t,
                                              (t == 0) ? 1 : 0, (t == T_ - 1) ? 1 : 0);
    }
  }
}

// Round 6
// 1608.208 us; speedup vs baseline: 1.0902x; 1.0902x over previous
//
#include <hip/hip_runtime.h>

// Problem constants
#define B_   16
#define T_   16
#define H_   161
#define W_   181
#define HW_  (H_*W_)     // 29141
#define C_   3
#define F_   21
#define F4_  84
#define TSX  32          // output tile width
#define TSY  8           // output tile height
#define NTAP 9
#define MT_  6           // m-tiles of 16 -> 96 gate rows (m = f*4+gate)
#define ROWB 128         // LDS bytes per position: 8 slots x 16B (4 k-groups x {hi,lo})
// Expanded region E: 34x10 at (bx0-1, by0-1). Staging S: 36x12 at (bx0-2, by0-2).
#define EPX 34
#define EPY 10
#define ENP (EPX*EPY)    // 340
#define SPX 36
#define SPY 12
#define SNP (SPX*SPY)    // 432
#define CPLS 344         // c-plane row stride (floats)
// ci map: 0..20 = h channels, 21..23 = pad, 24..26 = x, 27..31 = pad
#define GH_LO ((size_t)B_ * 3 * HW_)   // uint4 per gh plane (hi or lo)

typedef short bf16x8 __attribute__((ext_vector_type(8)));
typedef float f32x4  __attribute__((ext_vector_type(4)));

__device__ __forceinline__ float hsig(float x) {
  return fminf(fmaxf(0.2f * x + 0.5f, 0.0f), 1.0f);
}

__device__ __forceinline__ float fast_tanh(float x) {
  float ax = fabsf(x);
  float t = __expf(-2.0f * ax);
  float r = (1.0f - t) * __builtin_amdgcn_rcpf(1.0f + t);
  return copysignf(r, x);
}

__device__ __forceinline__ unsigned short bf16r(float x) {
  unsigned u = __float_as_uint(x);
  return (unsigned short)((u + 0x7FFFu + ((u >> 16) & 1u)) >> 16);
}
__device__ __forceinline__ void bsplit(float v, unsigned short& hi, unsigned short& lo) {
  hi = bf16r(v);
  float hf = __uint_as_float((unsigned)hi << 16);
  lo = bf16r(v - hf);
}

// A-fragment pack: Af[tap][mtg][hl][lane] (uint4 = 8 bf16). HW-verified r2.
__global__ void prep_kernel(const float* __restrict__ k,
                            const float* __restrict__ rk,
                            const float* __restrict__ bias,
                            unsigned short* __restrict__ Af,
                            float* __restrict__ bias4) {
  int i = blockIdx.x * 256 + threadIdx.x;
  if (i < NTAP * MT_ * 2 * 64 * 8) {
    int j    = i & 7;
    int lane = (i >> 3) & 63;
    int hl   = (i >> 9) & 1;
    int mtp  = i >> 10;
    int mt   = mtp % MT_;
    int tap  = mtp / MT_;
    int m    = mt * 16 + (lane & 15);
    int ci   = (lane >> 4) * 8 + j;
    int f    = m >> 2, gate = m & 3;
    float w = 0.0f;
    if (f < F_) {
      int oc = gate * F_ + f;
      if (ci < F_)                  w = rk[(tap * F_ + ci) * F4_ + oc];
      else if (ci >= 24 && ci < 27) w = k[(tap * C_ + (ci - 24)) * F4_ + oc];
    }
    unsigned short hb = bf16r(w);
    unsigned short outv;
    if (hl == 0) outv = hb;
    else {
      float hf = __uint_as_float((unsigned)hb << 16);
      outv = bf16r(w - hf);
    }
    Af[i] = outv;
  }
  if (i < 96) {
    int f = i >> 2, gate = i & 3;
    bias4[i] = (f < F_) ? bias[gate * F_ + f] : 0.0f;
  }
}

// ---------------- fused 2-step kernel ----------------
// Launch L handles t=2L (expanded 34x10, LDS-only outputs) and t+1 (interior 32x8).
// h_t and c_t never touch HBM. Numerics bitwise-identical to the 1-step kernel.
__global__ void __launch_bounds__(512, 4) step2_kernel(
    const float* __restrict__ x,        // (B,T,H,W,C) fp32
    const uint4* __restrict__ Af,       // [9][6][2][64] uint4
    const float* __restrict__ bias4,    // [24][4]
    const uint4* __restrict__ g_in,     // h_{t-1} bf16 hi/lo planes
    uint4* __restrict__ g_out,          // h_{t+1} bf16 hi/lo planes
    float* __restrict__ c_buf,          // (B,21,HW) fp32: holds c at odd steps
    const float* __restrict__ mask,
    float* __restrict__ out,            // (B,H,W,21) fp32, last launch only
    int t, int first, int last) {
  // LDS union: phase A/B-mfma: stg[432*128]=55296.
  // phase B-epi..C: til2[340*128]=43520 @0, cpl[24*344]f @43520 (33024) -> 76544.
  // phase D: bounce 2*12288 @0 (within dead til2), cpl still live.
  __shared__ uint4 ldsQ[4784];          // 76544 B -> 2 blocks/CU
  unsigned char* stg  = (unsigned char*)ldsQ;
  unsigned char* til2 = (unsigned char*)ldsQ;
  float* cpl = (float*)((char*)ldsQ + 43520);
  unsigned short* bh16 = (unsigned short*)ldsQ;
  unsigned short* bl16 = bh16 + 256 * 24;

  int b   = blockIdx.z;
  int by0 = blockIdx.y * TSY;
  int bx0 = blockIdx.x * TSX;
  int tid = threadIdx.x;

  // ---- phase A: stage S (36x12) with h_{t-1} (raw gh copies) + x_t ----
  for (int i = tid; i < 7 * SNP; i += 512) {
    int slot = i / SNP;
    int pos  = i - slot * SNP;
    int ey = pos / SPX, ex = pos - ey * SPX;
    int gy = by0 - 2 + ey, gx = bx0 - 2 + ex;
    bool inb = (unsigned)gy < (unsigned)H_ && (unsigned)gx < (unsigned)W_;
    int sw = pos & 7;
    if (slot < 6) {
      int g = slot >> 1, hl = slot & 1;
      uint4 v = {0u, 0u, 0u, 0u};
      if (!first && inb)
        v = g_in[(size_t)hl * GH_LO + (size_t)(b * 3 + g) * HW_ + gy * W_ + gx];
      *(uint4*)&stg[pos * ROWB + ((slot ^ sw) * 16)] = v;
    } else {
      float x0 = 0.f, x1 = 0.f, x2 = 0.f;
      if (inb) {
        const float* xp = x + (((size_t)(b * T_ + t) * H_ + gy) * W_ + gx) * C_;
        x0 = xp[0]; x1 = xp[1]; x2 = xp[2];
      }
      unsigned short h0, h1, h2, l0, l1, l2;
      bsplit(x0, h0, l0); bsplit(x1, h1, l1); bsplit(x2, h2, l2);
      uint4 vh = {(unsigned)h0 | ((unsigned)h1 << 16), (unsigned)h2, 0u, 0u};
      uint4 vl = {(unsigned)l0 | ((unsigned)l1 << 16), (unsigned)l2, 0u, 0u};
      *(uint4*)&stg[pos * ROWB + ((6 ^ sw) * 16)] = vh;
      *(uint4*)&stg[pos * ROWB + ((7 ^ sw) * 16)] = vl;
    }
  }
  __syncthreads();

  int lane = tid & 63;
  int wv   = tid >> 6;     // 0..7
  int wvn  = wv >> 1;      // n-group 0..3
  int wvm  = wv & 1;       // m-half 0..1
  int ln15 = lane & 15;
  int lg   = lane >> 4;

  // ---- phase B (mfma): step t gates over E (24 n-tiles of 16, 2 dead) ----
  f32x4 acc2[3][6];
#pragma unroll
  for (int mt = 0; mt < 3; ++mt)
#pragma unroll
    for (int j = 0; j < 6; ++j)
      acc2[mt][j] = (f32x4){0.f, 0.f, 0.f, 0.f};

#pragma unroll 1
  for (int tap = 0; tap < NTAP; ++tap) {
    int ky = tap / 3;
    int kx = tap - 3 * ky;

    bf16x8 eah[3], eal[3];
#pragma unroll
    for (int mt = 0; mt < 3; ++mt) {
      const uint4* ap = Af + (size_t)((tap * MT_ + (wvm * 3 + mt)) * 2) * 64 + lane;
      eah[mt] = __builtin_bit_cast(bf16x8, ap[0]);
      eal[mt] = __builtin_bit_cast(bf16x8, ap[64]);
    }

#pragma unroll
    for (int j = 0; j < 6; ++j) {
      int eb = (wvn * 6 + j) * 16;
      if (eb < ENP) {                      // skip fully-dead tiles (wvn=3, j>=4)
        int e  = eb + ln15;
        int ec = (e < ENP) ? e : 0;        // clamp dead lanes of partial tile
        int ey = ec / EPX, ex = ec - ey * EPX;
        int spos = (ey + ky) * SPX + ex + kx;
        int sw = spos & 7;
        uint4 hv = *(const uint4*)&stg[spos * ROWB + (((lg * 2 + 0) ^ sw) * 16)];
        uint4 lv = *(const uint4*)&stg[spos * ROWB + (((lg * 2 + 1) ^ sw) * 16)];
        bf16x8 bh = __builtin_bit_cast(bf16x8, hv);
        bf16x8 bl = __builtin_bit_cast(bf16x8, lv);
#pragma unroll
        for (int mt = 0; mt < 3; ++mt) {
          acc2[mt][j] = __builtin_amdgcn_mfma_f32_16x16x32_bf16(eah[mt], bh, acc2[mt][j], 0, 0, 0);
          acc2[mt][j] = __builtin_amdgcn_mfma_f32_16x16x32_bf16(eah[mt], bl, acc2[mt][j], 0, 0, 0);
          acc2[mt][j] = __builtin_amdgcn_mfma_f32_16x16x32_bf16(eal[mt], bh, acc2[mt][j], 0, 0, 0);
        }
      }
    }
  }
  __syncthreads();   // stg consumed; til2/cpl may now overwrite it

  // ---- phase B (epilogue): c_t -> cpl, h_t -> til2; x_{t+1} -> til2 ----
  float xv0 = 0.f, xv1 = 0.f, xv2 = 0.f;
  if (tid < ENP) {
    int ey = tid / EPX, ex = tid - ey * EPX;
    int gy = by0 - 1 + ey, gx = bx0 - 1 + ex;
    if ((unsigned)gy < (unsigned)H_ && (unsigned)gx < (unsigned)W_) {
      const float* xp = x + (((size_t)(b * T_ + t + 1) * H_ + gy) * W_ + gx) * C_;
      xv0 = xp[0]; xv1 = xp[1]; xv2 = xp[2];
    }
  }

#pragma unroll
  for (int mt = 0; mt < 3; ++mt) {
    int f = (wvm * 3 + mt) * 4 + lg;     // 0..23
    float4 bb = ((const float4*)bias4)[f];
#pragma unroll
    for (int j = 0; j < 6; ++j) {
      int e = (wvn * 6 + j) * 16 + ln15;
      if (e < ENP) {
        int ey = e / EPX, ex = e - ey * EPX;
        int gy = by0 - 1 + ey, gx = bx0 - 1 + ex;
        bool vld = (unsigned)gy < (unsigned)H_ && (unsigned)gx < (unsigned)W_;
        float cp = 0.0f;
        if (!first && vld && f < F_)
          cp = c_buf[((size_t)b * F_ + f) * HW_ + (size_t)gy * W_ + gx];
        float zi = acc2[mt][j][0] + bb.x;
        float zf = acc2[mt][j][1] + bb.y;
        float zc = acc2[mt][j][2] + bb.z;
        float zo = acc2[mt][j][3] + bb.w;
        float ig = hsig(zi);
        float fg = hsig(zf);
        float gg = fast_tanh(zc);
        float og = hsig(zo);
        float cn = fg * cp + ig * gg;
        float hn = og * fast_tanh(cn);
        if (!vld) { cn = 0.0f; hn = 0.0f; }   // OOB pixels must stage as zeros
        cpl[f * CPLS + e] = cn;
        unsigned short hh, hlw;
        bsplit(hn, hh, hlw);
        int sw = e & 7;
        int sb = (f >> 3) * 2;
        *(unsigned short*)&til2[e * ROWB + (((sb + 0) ^ sw) * 16) + (f & 7) * 2] = hh;
        *(unsigned short*)&til2[e * ROWB + (((sb + 1) ^ sw) * 16) + (f & 7) * 2] = hlw;
      }
    }
  }

  if (tid < ENP) {
    unsigned short h0, h1, h2, l0, l1, l2;
    bsplit(xv0, h0, l0); bsplit(xv1, h1, l1); bsplit(xv2, h2, l2);
    uint4 vh = {(unsigned)h0 | ((unsigned)h1 << 16), (unsigned)h2, 0u, 0u};
    uint4 vl = {(unsigned)l0 | ((unsigned)l1 << 16), (unsigned)l2, 0u, 0u};
    int sw = tid & 7;
    *(uint4*)&til2[tid * ROWB + ((6 ^ sw) * 16)] = vh;
    *(uint4*)&til2[tid * ROWB + ((7 ^ sw) * 16)] = vl;
  }
  __syncthreads();

  // ---- phase C: step t+1 gates over interior 32x8 (round-4 structure) ----
  f32x4 acc[3][4];
#pragma unroll
  for (int mt = 0; mt < 3; ++mt)
#pragma unroll
    for (int nt = 0; nt < 4; ++nt)
      acc[mt][nt] = (f32x4){0.f, 0.f, 0.f, 0.f};

#pragma unroll 1
  for (int tap = 0; tap < NTAP; ++tap) {
    int ky = tap / 3;
    int kx = tap - 3 * ky;

    bf16x8 bh[4], bl[4];
#pragma unroll
    for (int nt = 0; nt < 4; ++nt) {
      int pos = (wvn * 2 + (nt >> 1) + ky) * EPX + (nt & 1) * 16 + ln15 + kx;
      int sw  = pos & 7;
      uint4 hv = *(const uint4*)&til2[pos * ROWB + (((lg * 2 + 0) ^ sw) * 16)];
      uint4 lv = *(const uint4*)&til2[pos * ROWB + (((lg * 2 + 1) ^ sw) * 16)];
      bh[nt] = __builtin_bit_cast(bf16x8, hv);
      bl[nt] = __builtin_bit_cast(bf16x8, lv);
    }

#pragma unroll
    for (int mt = 0; mt < 3; ++mt) {
      const uint4* ap = Af + (size_t)((tap * MT_ + (wvm * 3 + mt)) * 2) * 64 + lane;
      bf16x8 ah = __builtin_bit_cast(bf16x8, ap[0]);
      bf16x8 al = __builtin_bit_cast(bf16x8, ap[64]);
#pragma unroll
      for (int nt = 0; nt < 4; ++nt) {
        acc[mt][nt] = __builtin_amdgcn_mfma_f32_16x16x32_bf16(ah, bh[nt], acc[mt][nt], 0, 0, 0);
        acc[mt][nt] = __builtin_amdgcn_mfma_f32_16x16x32_bf16(ah, bl[nt], acc[mt][nt], 0, 0, 0);
        acc[mt][nt] = __builtin_amdgcn_mfma_f32_16x16x32_bf16(al, bh[nt], acc[mt][nt], 0, 0, 0);
      }
    }
  }
  __syncthreads();   // til2 consumed; bounce may overwrite it (cpl untouched)

  // ---- phase D: step t+1 epilogue; c from cpl; h_{t+1} -> bounce ----
#pragma unroll
  for (int mt = 0; mt < 3; ++mt) {
    int f = (wvm * 3 + mt) * 4 + lg;
    float4 bb = ((const float4*)bias4)[f];
#pragma unroll
    for (int nt = 0; nt < 4; ++nt) {
      int py = wvn * 2 + (nt >> 1);
      int px = (nt & 1) * 16 + ln15;
      int gy = by0 + py, gx = bx0 + px;
      if (gy < H_ && gx < W_) {
        int    pixL = py * TSX + px;
        int    e    = (py + 1) * EPX + (px + 1);
        size_t gpix = (size_t)gy * W_ + gx;
        float cp = cpl[f * CPLS + e];
        float zi = acc[mt][nt][0] + bb.x;
        float zf = acc[mt][nt][1] + bb.y;
        float zc = acc[mt][nt][2] + bb.z;
        float zo = acc[mt][nt][3] + bb.w;
        float ig = hsig(zi);
        float fg = hsig(zf);
        float gg = fast_tanh(zc);
        float og = hsig(zo);
        float cn = fg * cp + ig * gg;
        float hn = og * fast_tanh(cn);
        if (f < F_ && !last) c_buf[((size_t)b * F_ + f) * HW_ + gpix] = cn;
        if (last) {
          if (f < F_)
            out[((size_t)(b * H_ + gy) * W_ + gx) * F_ + f] = hn * mask[gpix];
        } else {
          unsigned short hh, hlw;
          bsplit(hn, hh, hlw);
          bh16[pixL * 24 + f] = hh;
          bl16[pixL * 24 + f] = hlw;
        }
      }
    }
  }

  if (last) return;
  __syncthreads();

  // ---- pack bounce -> g_out (h_{t+1}) ----
  for (int i = tid; i < 256 * 3 * 2; i += 512) {
    int hl   = (i >= 768) ? 1 : 0;
    int j    = i - hl * 768;
    int g    = j >> 8;
    int pixL = j & 255;
    int py = pixL >> 5, px = pixL & 31;
    int gy = by0 + py, gx = bx0 + px;
    if (gy < H_ && gx < W_) {
      const unsigned short* src = (hl ? bl16 : bh16) + pixL * 24 + g * 8;
      uint4 v = *(const uint4*)src;
      g_out[(size_t)hl * GH_LO + (size_t)(b * 3 + g) * HW_ + (size_t)gy * W_ + gx] = v;
    }
  }
}

// ---------------- fallback path (round-2 proven kernel, ~78 MB ws) ----------------
#define TPX  34
#define TPY  10
#define NPOS (TPX*TPY)
__global__ void __launch_bounds__(256, 3) step_kernel_f(
    const float* __restrict__ x,
    const uint4* __restrict__ Af,
    const float* __restrict__ bias4,
    const float* __restrict__ h_in,
    float* __restrict__ h_out,
    float* __restrict__ c_buf,
    const float* __restrict__ mask,
    float* __restrict__ out,
    int t, int first, int last) {
  __shared__ uint4 tileQ[NPOS * 8];
  unsigned char* tile = (unsigned char*)tileQ;

  int b   = blockIdx.z;
  int by0 = blockIdx.y * TSY;
  int bx0 = blockIdx.x * TSX;
  int tid = threadIdx.x;

  for (int i = tid; i < 32 * NPOS; i += 256) {
    int ci  = i / NPOS;
    int pos = i - ci * NPOS;
    int py = pos / TPX, px = pos - py * TPX;
    int gy = by0 - 1 + py, gx = bx0 - 1 + px;
    float v = 0.0f;
    if ((unsigned)gy < (unsigned)H_ && (unsigned)gx < (unsigned)W_) {
      if (ci < F_) {
        if (!first) v = h_in[(size_t)(b * F_ + ci) * HW_ + gy * W_ + gx];
      } else if (ci >= 24 && ci < 27) {
        v = x[(((size_t)(b * T_ + t) * H_ + gy) * W_ + gx) * C_ + (ci - 24)];
      }
    }
    unsigned short hb, lb;
    bsplit(v, hb, lb);
    int g  = ci >> 3, e = ci & 7, sw = pos & 7;
    *(unsigned short*)&tile[pos * ROWB + (((g * 2 + 0) ^ sw) * 16) + e * 2] = hb;
    *(unsigned short*)&tile[pos * ROWB + (((g * 2 + 1) ^ sw) * 16) + e * 2] = lb;
  }
  __syncthreads();

  int lane = tid & 63;
  int wv   = tid >> 6;
  int ln15 = lane & 15;
  int lg   = lane >> 4;

  f32x4 acc[MT_][4];
#pragma unroll
  for (int mt = 0; mt < MT_; ++mt)
#pragma unroll
    for (int nt = 0; nt < 4; ++nt)
      acc[mt][nt] = (f32x4){0.f, 0.f, 0.f, 0.f};

#pragma unroll 1
  for (int tap = 0; tap < NTAP; ++tap) {
    int ky = tap / 3;
    int kx = tap - 3 * ky;

    bf16x8 bh[4], bl[4];
#pragma unroll
    for (int nt = 0; nt < 4; ++nt) {
      int pos = (wv * 2 + (nt >> 1) + ky) * TPX + (nt & 1) * 16 + ln15 + kx;
      int sw  = pos & 7;
      uint4 hv = *(const uint4*)&tile[pos * ROWB + (((lg * 2 + 0) ^ sw) * 16)];
      uint4 lv = *(const uint4*)&tile[pos * ROWB + (((lg * 2 + 1) ^ sw) * 16)];
      bh[nt] = __builtin_bit_cast(bf16x8, hv);
      bl[nt] = __builtin_bit_cast(bf16x8, lv);
    }

#pragma unroll
    for (int mt = 0; mt < MT_; ++mt) {
      const uint4* ap = Af + (size_t)((tap * MT_ + mt) * 2) * 64 + lane;
      bf16x8 ah = __builtin_bit_cast(bf16x8, ap[0]);
      bf16x8 al = __builtin_bit_cast(bf16x8, ap[64]);
#pragma unroll
      for (int nt = 0; nt < 4; ++nt) {
        acc[mt][nt] = __builtin_amdgcn_mfma_f32_16x16x32_bf16(ah, bh[nt], acc[mt][nt], 0, 0, 0);
        acc[mt][nt] = __builtin_amdgcn_mfma_f32_16x16x32_bf16(ah, bl[nt], acc[mt][nt], 0, 0, 0);
        acc[mt][nt] = __builtin_amdgcn_mfma_f32_16x16x32_bf16(al, bh[nt], acc[mt][nt], 0, 0, 0);
      }
    }
  }

#pragma unroll
  for (int mt = 0; mt < MT_; ++mt) {
    int f = mt * 4 + lg;
    if (f < F_) {
      float4 bb = ((const float4*)bias4)[f];
#pragma unroll
      for (int nt = 0; nt < 4; ++nt) {
        int gy = by0 + wv * 2 + (nt >> 1);
        int gx = bx0 + (nt & 1) * 16 + ln15;
        if (gy < H_ && gx < W_) {
          size_t idx = ((size_t)b * F_ + f) * HW_ + (size_t)gy * W_ + gx;
          float zi = acc[mt][nt][0] + bb.x;
          float zf = acc[mt][nt][1] + bb.y;
          float zc = acc[mt][nt][2] + bb.z;
          float zo = acc[mt][nt][3] + bb.w;
          float ig = hsig(zi);
          float fg = hsig(zf);
          float gg = fast_tanh(zc);
          float og = hsig(zo);
          float cp = first ? 0.0f : c_buf[idx];
          float cn = fg * cp + ig * gg;
          float hn = og * fast_tanh(cn);
          c_buf[idx] = cn;
          if (!last) h_out[idx] = hn;
          else {
            out[((size_t)(b * H_ + gy) * W_ + gx) * F_ + f] =
                hn * mask[(size_t)gy * W_ + gx];
          }
        }
      }
    }
  }
}

extern "C" void kernel_launch(void* const* d_in, const int* in_sizes, int n_in,
                              void* d_out, int out_size, void* d_ws, size_t ws_size,
                              hipStream_t stream) {
  const float* x  = (const float*)d_in[0];
  const float* k  = (const float*)d_in[1];
  const float* rk = (const float*)d_in[2];
  const float* bs = (const float*)d_in[3];
  const float* mk = (const float*)d_in[4];
  float* outF = (float*)d_out;

  char* ws = (char*)d_ws;
  unsigned short* Af = (unsigned short*)ws;          // 110592 B
  float* bias4 = (float*)(ws + 110592);              // 384 B
  size_t off = (size_t)((110592 + 384 + 255) & ~255);
  size_t HWF = (size_t)B_ * H_ * W_ * F_;

  prep_kernel<<<dim3((NTAP * MT_ * 2 * 64 * 8 + 255) / 256), 256, 0, stream>>>(
      k, rk, bs, Af, bias4);

  dim3 grid((W_ + TSX - 1) / TSX, (H_ + TSY - 1) / TSY, B_);  // (6, 21, 16)

  size_t need_packed = off + (size_t)4 * GH_LO * 16 + HWF * 4;  // ~128.8 MB

  if (ws_size >= need_packed) {
    uint4* ghA = (uint4*)(ws + off);
    uint4* ghB = ghA + 2 * GH_LO;
    float* cB  = (float*)(ghB + 2 * GH_LO);
    for (int L = 0; L < T_ / 2; ++L) {
      const uint4* gin = (L & 1) ? ghB : ghA;
      uint4* gout      = (L & 1) ? ghA : ghB;
      step2_kernel<<<grid, 512, 0, stream>>>(x, (const uint4*)Af, bias4, gin, gout,
                                             cB, mk, outF, 2 * L,
                                             (L == 0) ? 1 : 0,
                                             (L == T_ / 2 - 1) ? 1 : 0);
    }
  } else {
    float* hA = (float*)(ws + off);
    float* cB = hA + HWF;
    for (int t = 0; t < T_; ++t) {
      const float* hi = (t & 1) ? hA : outF;
      float* ho       = (t & 1) ? outF : hA;
      step_kernel_f<<<grid, 256, 0, stream>>>(x, (const uint4*)Af, bias4, hi, ho,
                                              cB, mk, outF, t,
                                              (t == 0) ? 1 : 0, (t == T_ - 1) ? 1 : 0);
    }
  }
}

// Round 7
// 1543.977 us; speedup vs baseline: 1.1356x; 1.0416x over previous
//
#include <hip/hip_runtime.h>

// Problem constants
#define B_   16
#define T_   16
#define H_   161
#define W_   181
#define HW_  (H_*W_)     // 29141
#define C_   3
#define F_   21
#define F4_  84
#define TSX  32          // tile width
#define TSY  8           // tile height (256 px per block)
#define TPX  34          // tile + halo
#define TPY  10
#define NPOS (TPX*TPY)   // 340
#define NTAP 9
#define MT_  6           // m-tiles of 16 -> 96 gate rows (m = f*4+gate)
#define ROWB 128         // LDS bytes per position: 8 slots x 16B (4 k-groups x {hi,lo})
// ci map: 0..20 = h channels, 21..23 = pad, 24..26 = x, 27..31 = pad
#define GH_LO ((size_t)B_ * 3 * HW_)   // uint4 elements per gh plane (hi or lo)

typedef short bf16x8 __attribute__((ext_vector_type(8)));
typedef float f32x4  __attribute__((ext_vector_type(4)));

__device__ __forceinline__ float hsig(float x) {
  return fminf(fmaxf(0.2f * x + 0.5f, 0.0f), 1.0f);
}

__device__ __forceinline__ float fast_tanh(float x) {
  float ax = fabsf(x);
  float t = __expf(-2.0f * ax);
  float r = (1.0f - t) * __builtin_amdgcn_rcpf(1.0f + t);
  return copysignf(r, x);
}

// round-to-nearest-even fp32 -> bf16 bits
__device__ __forceinline__ unsigned short bf16r(float x) {
  unsigned u = __float_as_uint(x);
  return (unsigned short)((u + 0x7FFFu + ((u >> 16) & 1u)) >> 16);
}
__device__ __forceinline__ void bsplit(float v, unsigned short& hi, unsigned short& lo) {
  hi = bf16r(v);
  float hf = __uint_as_float((unsigned)hi << 16);
  lo = bf16r(v - hf);
}

// A-fragment pack: Af[tap][mt][hl][lane] (uint4 = 8 bf16). HW-verified r2.
// mfma_f32_16x16x32_bf16 A layout: row m = lane&15, k = (lane>>4)*8 + j.
// m = f*4 + gate; oc = gate*21 + f (Keras i,f,c,o).
__global__ void prep_kernel(const float* __restrict__ k,
                            const float* __restrict__ rk,
                            const float* __restrict__ bias,
                            unsigned short* __restrict__ Af,
                            float* __restrict__ bias4) {
  int i = blockIdx.x * 256 + threadIdx.x;
  if (i < NTAP * MT_ * 2 * 64 * 8) {
    int j    = i & 7;
    int lane = (i >> 3) & 63;
    int hl   = (i >> 9) & 1;
    int mtp  = i >> 10;          // tap*MT_ + mt
    int mt   = mtp % MT_;
    int tap  = mtp / MT_;
    int m    = mt * 16 + (lane & 15);
    int ci   = (lane >> 4) * 8 + j;
    int f    = m >> 2, gate = m & 3;
    float w = 0.0f;
    if (f < F_) {
      int oc = gate * F_ + f;
      if (ci < F_)                  w = rk[(tap * F_ + ci) * F4_ + oc];
      else if (ci >= 24 && ci < 27) w = k[(tap * C_ + (ci - 24)) * F4_ + oc];
    }
    unsigned short hb = bf16r(w);
    unsigned short outv;
    if (hl == 0) outv = hb;
    else {
      float hf = __uint_as_float((unsigned)hb << 16);
      outv = bf16r(w - hf);
    }
    Af[i] = outv;
  }
  if (i < 96) {   // bias4[f][gate], f padded to 24
    int f = i >> 2, gate = i & 3;
    bias4[i] = (f < F_) ? bias[gate * F_ + f] : 0.0f;
  }
}

// ---------------- packed-h 1-step kernel, register-lean ----------------
// grid (6,21,16), block 768 (12 waves): wvm = wv>>1 owns ONE m-tile (acc 32
// regs/wave), wvn = wv&1 owns a 32x4 pixel half (8 n-tiles). 2 blocks/CU x 12
// waves = 24 waves/CU = 6/SIMD (vs 4 before): +50% latency hiding.
// A-fragment loads drop to 18/wave (one (ah,al) pair per tap).
// Per-output MFMA order identical to round 4 -> bitwise-identical numerics.
__global__ void __launch_bounds__(768, 6) step_kernel_p(
    const float* __restrict__ x,        // (B,T,H,W,C) fp32
    const uint4* __restrict__ Af,       // [9][6][2][64] uint4
    const float* __restrict__ bias4,    // [24][4]
    const uint4* __restrict__ g_in,     // h bf16 hi/lo planes (prev step)
    uint4* __restrict__ g_out,          // h bf16 hi/lo planes (this step)
    float* __restrict__ c_buf,          // (B,21,HW) fp32 in-place
    const float* __restrict__ mask,     // (H,W,1)
    float* __restrict__ out,            // (B,H,W,21) fp32, last step only
    int t, int first, int last) {
  __shared__ uint4 tileQ[NPOS * 8];     // 43520 B -> 2 blocks/CU (reg-lean waves)
  unsigned char* tile = (unsigned char*)tileQ;
  unsigned short* bh16 = (unsigned short*)tileQ;   // epilogue bounce hi: [256][24]
  unsigned short* bl16 = bh16 + 256 * 24;          // bounce lo (offset 12288 B)

  int b   = blockIdx.z;
  int by0 = blockIdx.y * TSY;
  int bx0 = blockIdx.x * TSX;
  int tid = threadIdx.x;

  // ---- stage tile: h groups are raw 16B copies; x converted on the fly ----
  for (int i = tid; i < 7 * NPOS; i += 768) {
    int slot = i / NPOS;              // 0..5: h groups (g*2+hl); 6: x
    int pos  = i - slot * NPOS;
    int py = pos / TPX, px = pos - py * TPX;
    int gy = by0 - 1 + py, gx = bx0 - 1 + px;
    bool inb = (unsigned)gy < (unsigned)H_ && (unsigned)gx < (unsigned)W_;
    int sw = pos & 7;
    if (slot < 6) {
      int g = slot >> 1, hl = slot & 1;
      uint4 v = {0u, 0u, 0u, 0u};
      if (!first && inb)
        v = g_in[(size_t)hl * GH_LO + (size_t)(b * 3 + g) * HW_ + gy * W_ + gx];
      *(uint4*)&tile[pos * ROWB + ((slot ^ sw) * 16)] = v;
    } else {
      float x0 = 0.f, x1 = 0.f, x2 = 0.f;
      if (inb) {
        const float* xp = x + (((size_t)(b * T_ + t) * H_ + gy) * W_ + gx) * C_;
        x0 = xp[0]; x1 = xp[1]; x2 = xp[2];
      }
      unsigned short h0, h1, h2, l0, l1, l2;
      bsplit(x0, h0, l0); bsplit(x1, h1, l1); bsplit(x2, h2, l2);
      uint4 vh = {(unsigned)h0 | ((unsigned)h1 << 16), (unsigned)h2, 0u, 0u};
      uint4 vl = {(unsigned)l0 | ((unsigned)l1 << 16), (unsigned)l2, 0u, 0u};
      *(uint4*)&tile[pos * ROWB + ((6 ^ sw) * 16)] = vh;
      *(uint4*)&tile[pos * ROWB + ((7 ^ sw) * 16)] = vl;
    }
  }
  __syncthreads();

  int lane = tid & 63;
  int wv   = tid >> 6;     // 0..11
  int wvm  = wv >> 1;      // m-tile 0..5 (one per wave)
  int wvn  = wv & 1;       // pixel half: rows wvn*4 .. wvn*4+3
  int ln15 = lane & 15;
  int lg   = lane >> 4;

  f32x4 acc[8];
#pragma unroll
  for (int nt = 0; nt < 8; ++nt)
    acc[nt] = (f32x4){0.f, 0.f, 0.f, 0.f};

#pragma unroll 1
  for (int tap = 0; tap < NTAP; ++tap) {
    int ky = tap / 3;
    int kx = tap - 3 * ky;

    const uint4* ap = Af + (size_t)((tap * MT_ + wvm) * 2) * 64 + lane;
    bf16x8 ah = __builtin_bit_cast(bf16x8, ap[0]);
    bf16x8 al = __builtin_bit_cast(bf16x8, ap[64]);

#pragma unroll
    for (int nt = 0; nt < 8; ++nt) {
      int pos = (wvn * 4 + (nt >> 1) + ky) * TPX + (nt & 1) * 16 + ln15 + kx;
      int sw  = pos & 7;
      uint4 hv = *(const uint4*)&tile[pos * ROWB + (((lg * 2 + 0) ^ sw) * 16)];
      uint4 lv = *(const uint4*)&tile[pos * ROWB + (((lg * 2 + 1) ^ sw) * 16)];
      bf16x8 bh = __builtin_bit_cast(bf16x8, hv);
      bf16x8 bl = __builtin_bit_cast(bf16x8, lv);
      acc[nt] = __builtin_amdgcn_mfma_f32_16x16x32_bf16(ah, bh, acc[nt], 0, 0, 0);
      acc[nt] = __builtin_amdgcn_mfma_f32_16x16x32_bf16(ah, bl, acc[nt], 0, 0, 0);
      acc[nt] = __builtin_amdgcn_mfma_f32_16x16x32_bf16(al, bh, acc[nt], 0, 0, 0);
    }
  }

  __syncthreads();   // tile consumed by all waves; reuse LDS as epilogue bounce

  // ---- lane-local LSTM epilogue; h -> bounce LDS as split bf16 ----
  int f = wvm * 4 + lg;                 // 0..23 (21..23 -> finite junk, zero-weighted)
  float4 bb = ((const float4*)bias4)[f];
#pragma unroll
  for (int nt = 0; nt < 8; ++nt) {
    int py = wvn * 4 + (nt >> 1);
    int px = (nt & 1) * 16 + ln15;
    int gy = by0 + py, gx = bx0 + px;
    if (gy < H_ && gx < W_) {
      int    pixL = py * TSX + px;
      size_t gpix = (size_t)gy * W_ + gx;
      float zi = acc[nt][0] + bb.x;
      float zf = acc[nt][1] + bb.y;
      float zc = acc[nt][2] + bb.z;
      float zo = acc[nt][3] + bb.w;
      float ig = hsig(zi);
      float fg = hsig(zf);
      float gg = fast_tanh(zc);
      float og = hsig(zo);
      float cp = (first || f >= F_) ? 0.0f
                                    : c_buf[((size_t)b * F_ + f) * HW_ + gpix];
      float cn = fg * cp + ig * gg;
      float hn = og * fast_tanh(cn);
      if (f < F_ && !last) c_buf[((size_t)b * F_ + f) * HW_ + gpix] = cn;
      if (last) {
        if (f < F_)
          out[((size_t)(b * H_ + gy) * W_ + gx) * F_ + f] = hn * mask[gpix];
      } else {
        unsigned short hh, hlw;
        bsplit(hn, hh, hlw);
        bh16[pixL * 24 + f] = hh;
        bl16[pixL * 24 + f] = hlw;
      }
    }
  }

  if (last) return;
  __syncthreads();

  // ---- pack bounce -> g_out (coalesced 16B stores) ----
  for (int i = tid; i < 256 * 3 * 2; i += 768) {
    int hl   = (i >= 768) ? 1 : 0;
    int j    = i - hl * 768;
    int g    = j >> 8;
    int pixL = j & 255;
    int py = pixL >> 5, px = pixL & 31;
    int gy = by0 + py, gx = bx0 + px;
    if (gy < H_ && gx < W_) {
      const unsigned short* src = (hl ? bl16 : bh16) + pixL * 24 + g * 8;
      uint4 v = *(const uint4*)src;
      g_out[(size_t)hl * GH_LO + (size_t)(b * 3 + g) * HW_ + (size_t)gy * W_ + gx] = v;
    }
  }
}

// ---------------- fallback path (round-2 proven kernel, ~78 MB ws) ----------------
__global__ void __launch_bounds__(256, 3) step_kernel_f(
    const float* __restrict__ x,
    const uint4* __restrict__ Af,
    const float* __restrict__ bias4,
    const float* __restrict__ h_in,     // (B,F,HW) fp32
    float* __restrict__ h_out,          // (B,F,HW) fp32
    float* __restrict__ c_buf,
    const float* __restrict__ mask,
    float* __restrict__ out,
    int t, int first, int last) {
  __shared__ uint4 tileQ[NPOS * 8];
  unsigned char* tile = (unsigned char*)tileQ;

  int b   = blockIdx.z;
  int by0 = blockIdx.y * TSY;
  int bx0 = blockIdx.x * TSX;
  int tid = threadIdx.x;

  for (int i = tid; i < 32 * NPOS; i += 256) {
    int ci  = i / NPOS;
    int pos = i - ci * NPOS;
    int py = pos / TPX, px = pos - py * TPX;
    int gy = by0 - 1 + py, gx = bx0 - 1 + px;
    float v = 0.0f;
    if ((unsigned)gy < (unsigned)H_ && (unsigned)gx < (unsigned)W_) {
      if (ci < F_) {
        if (!first) v = h_in[(size_t)(b * F_ + ci) * HW_ + gy * W_ + gx];
      } else if (ci >= 24 && ci < 27) {
        v = x[(((size_t)(b * T_ + t) * H_ + gy) * W_ + gx) * C_ + (ci - 24)];
      }
    }
    unsigned short hb, lb;
    bsplit(v, hb, lb);
    int g  = ci >> 3, e = ci & 7, sw = pos & 7;
    *(unsigned short*)&tile[pos * ROWB + (((g * 2 + 0) ^ sw) * 16) + e * 2] = hb;
    *(unsigned short*)&tile[pos * ROWB + (((g * 2 + 1) ^ sw) * 16) + e * 2] = lb;
  }
  __syncthreads();

  int lane = tid & 63;
  int wv   = tid >> 6;
  int ln15 = lane & 15;
  int lg   = lane >> 4;

  f32x4 acc[MT_][4];
#pragma unroll
  for (int mt = 0; mt < MT_; ++mt)
#pragma unroll
    for (int nt = 0; nt < 4; ++nt)
      acc[mt][nt] = (f32x4){0.f, 0.f, 0.f, 0.f};

#pragma unroll 1
  for (int tap = 0; tap < NTAP; ++tap) {
    int ky = tap / 3;
    int kx = tap - 3 * ky;

    bf16x8 bh[4], bl[4];
#pragma unroll
    for (int nt = 0; nt < 4; ++nt) {
      int pos = (wv * 2 + (nt >> 1) + ky) * TPX + (nt & 1) * 16 + ln15 + kx;
      int sw  = pos & 7;
      uint4 hv = *(const uint4*)&tile[pos * ROWB + (((lg * 2 + 0) ^ sw) * 16)];
      uint4 lv = *(const uint4*)&tile[pos * ROWB + (((lg * 2 + 1) ^ sw) * 16)];
      bh[nt] = __builtin_bit_cast(bf16x8, hv);
      bl[nt] = __builtin_bit_cast(bf16x8, lv);
    }

#pragma unroll
    for (int mt = 0; mt < MT_; ++mt) {
      const uint4* ap = Af + (size_t)((tap * MT_ + mt) * 2) * 64 + lane;
      bf16x8 ah = __builtin_bit_cast(bf16x8, ap[0]);
      bf16x8 al = __builtin_bit_cast(bf16x8, ap[64]);
#pragma unroll
      for (int nt = 0; nt < 4; ++nt) {
        acc[mt][nt] = __builtin_amdgcn_mfma_f32_16x16x32_bf16(ah, bh[nt], acc[mt][nt], 0, 0, 0);
        acc[mt][nt] = __builtin_amdgcn_mfma_f32_16x16x32_bf16(ah, bl[nt], acc[mt][nt], 0, 0, 0);
        acc[mt][nt] = __builtin_amdgcn_mfma_f32_16x16x32_bf16(al, bh[nt], acc[mt][nt], 0, 0, 0);
      }
    }
  }

#pragma unroll
  for (int mt = 0; mt < MT_; ++mt) {
    int f = mt * 4 + lg;
    if (f < F_) {
      float4 bb = ((const float4*)bias4)[f];
#pragma unroll
      for (int nt = 0; nt < 4; ++nt) {
        int gy = by0 + wv * 2 + (nt >> 1);
        int gx = bx0 + (nt & 1) * 16 + ln15;
        if (gy < H_ && gx < W_) {
          size_t idx = ((size_t)b * F_ + f) * HW_ + (size_t)gy * W_ + gx;
          float zi = acc[mt][nt][0] + bb.x;
          float zf = acc[mt][nt][1] + bb.y;
          float zc = acc[mt][nt][2] + bb.z;
          float zo = acc[mt][nt][3] + bb.w;
          float ig = hsig(zi);
          float fg = hsig(zf);
          float gg = fast_tanh(zc);
          float og = hsig(zo);
          float cp = first ? 0.0f : c_buf[idx];
          float cn = fg * cp + ig * gg;
          float hn = og * fast_tanh(cn);
          c_buf[idx] = cn;
          if (!last) h_out[idx] = hn;
          else {
            out[((size_t)(b * H_ + gy) * W_ + gx) * F_ + f] =
                hn * mask[(size_t)gy * W_ + gx];
          }
        }
      }
    }
  }
}

extern "C" void kernel_launch(void* const* d_in, const int* in_sizes, int n_in,
                              void* d_out, int out_size, void* d_ws, size_t ws_size,
                              hipStream_t stream) {
  const float* x  = (const float*)d_in[0];
  const float* k  = (const float*)d_in[1];
  const float* rk = (const float*)d_in[2];
  const float* bs = (const float*)d_in[3];
  const float* mk = (const float*)d_in[4];
  float* outF = (float*)d_out;

  char* ws = (char*)d_ws;
  unsigned short* Af = (unsigned short*)ws;          // 110592 B
  float* bias4 = (float*)(ws + 110592);              // 384 B
  size_t off = (size_t)((110592 + 384 + 255) & ~255);
  size_t HWF = (size_t)B_ * H_ * W_ * F_;

  prep_kernel<<<dim3((NTAP * MT_ * 2 * 64 * 8 + 255) / 256), 256, 0, stream>>>(
      k, rk, bs, Af, bias4);

  dim3 grid((W_ + TSX - 1) / TSX, (H_ + TSY - 1) / TSY, B_);  // (6, 21, 16)

  size_t need_packed = off + (size_t)4 * GH_LO * 16 + HWF * 4;  // ~128.8 MB

  if (ws_size >= need_packed) {
    // packed-h path: ghA/ghB = split-bf16 h planes, c fp32
    uint4* ghA = (uint4*)(ws + off);
    uint4* ghB = ghA + 2 * GH_LO;
    float* cB  = (float*)(ghB + 2 * GH_LO);
    for (int t = 0; t < T_; ++t) {
      const uint4* gin = (t & 1) ? ghB : ghA;
      uint4* gout      = (t & 1) ? ghA : ghB;
      step_kernel_p<<<grid, 768, 0, stream>>>(x, (const uint4*)Af, bias4, gin, gout,
                                              cB, mk, outF, t,
                                              (t == 0) ? 1 : 0, (t == T_ - 1) ? 1 : 0);
    }
  } else {
    // fallback (round-2 proven): fp32 h ping-pong via ws + outF, ~78.4 MB
    float* hA = (float*)(ws + off);
    float* cB = hA + HWF;
    for (int t = 0; t < T_; ++t) {
      const float* hi = (t & 1) ? hA : outF;
      float* ho       = (t & 1) ? outF : hA;
      step_kernel_f<<<grid, 256, 0, stream>>>(x, (const uint4*)Af, bias4, hi, ho,
                                              cB, mk, outF, t,
                                              (t == 0) ? 1 : 0, (t == T_ - 1) ? 1 : 0);
    }
  }
}

// Round 8
// 1520.950 us; speedup vs baseline: 1.1528x; 1.0151x over previous
//
#include <hip/hip_runtime.h>

// Problem constants
#define B_   16
#define T_   16
#define H_   161
#define W_   181
#define HW_  (H_*W_)     // 29141
#define C_   3
#define F_   21
#define F4_  84
#define TSX  32          // tile width
#define TSY  8           // tile height (256 px per block)
#define TPX  34          // tile + halo
#define TPY  10
#define NPOS (TPX*TPY)   // 340
#define NTAP 9
#define MT_  6           // m-tiles of 16 -> 96 gate rows (m = f*4+gate)
#define ROWB 128         // LDS bytes per position: 8 slots x 16B (4 k-groups x {hi,lo})
// ci map: 0..20 = h channels, 21..23 = pad, 24..26 = x, 27..31 = pad
#define GH_LO ((size_t)B_ * 3 * HW_)   // uint4 elements per gh plane (hi or lo)

typedef short bf16x8 __attribute__((ext_vector_type(8)));
typedef float f32x4  __attribute__((ext_vector_type(4)));

__device__ __forceinline__ float hsig(float x) {
  return fminf(fmaxf(0.2f * x + 0.5f, 0.0f), 1.0f);
}

__device__ __forceinline__ float fast_tanh(float x) {
  float ax = fabsf(x);
  float t = __expf(-2.0f * ax);
  float r = (1.0f - t) * __builtin_amdgcn_rcpf(1.0f + t);
  return copysignf(r, x);
}

// round-to-nearest-even fp32 -> bf16 bits
__device__ __forceinline__ unsigned short bf16r(float x) {
  unsigned u = __float_as_uint(x);
  return (unsigned short)((u + 0x7FFFu + ((u >> 16) & 1u)) >> 16);
}
__device__ __forceinline__ void bsplit(float v, unsigned short& hi, unsigned short& lo) {
  hi = bf16r(v);
  float hf = __uint_as_float((unsigned)hi << 16);
  lo = bf16r(v - hf);
}

// A-fragment pack: Af[tap][mt][hl][lane] (uint4 = 8 bf16). HW-verified r2.
// mfma_f32_16x16x32_bf16 A layout: row m = lane&15, k = (lane>>4)*8 + j.
// m = f*4 + gate; oc = gate*21 + f (Keras i,f,c,o).
__global__ void prep_kernel(const float* __restrict__ k,
                            const float* __restrict__ rk,
                            const float* __restrict__ bias,
                            unsigned short* __restrict__ Af,
                            float* __restrict__ bias4) {
  int i = blockIdx.x * 256 + threadIdx.x;
  if (i < NTAP * MT_ * 2 * 64 * 8) {
    int j    = i & 7;
    int lane = (i >> 3) & 63;
    int hl   = (i >> 9) & 1;
    int mtp  = i >> 10;          // tap*MT_ + mt
    int mt   = mtp % MT_;
    int tap  = mtp / MT_;
    int m    = mt * 16 + (lane & 15);
    int ci   = (lane >> 4) * 8 + j;
    int f    = m >> 2, gate = m & 3;
    float w = 0.0f;
    if (f < F_) {
      int oc = gate * F_ + f;
      if (ci < F_)                  w = rk[(tap * F_ + ci) * F4_ + oc];
      else if (ci >= 24 && ci < 27) w = k[(tap * C_ + (ci - 24)) * F4_ + oc];
    }
    unsigned short hb = bf16r(w);
    unsigned short outv;
    if (hl == 0) outv = hb;
    else {
      float hf = __uint_as_float((unsigned)hb << 16);
      outv = bf16r(w - hf);
    }
    Af[i] = outv;
  }
  if (i < 96) {   // bias4[f][gate], f padded to 24
    int f = i >> 2, gate = i & 3;
    bias4[i] = (f < F_) ? bias[gate * F_ + f] : 0.0f;
  }
}

// ---------------- packed-h 1-step kernel ----------------
// grid (6,21,16), block 768 (12 waves): wvm = wv>>2 (0..2) owns m-tiles
// {2wvm, 2wvm+1}; wvn = wv&3 owns rows {2wvn, 2wvn+1} (4 n-tiles).
// acc 2x4 f32x4 = 32 regs; A 2 pairs (16); B transient (8) -> ~80 total,
// __launch_bounds__(768,6) => 2 blocks/CU, 24 waves/CU = 6/SIMD.
// Each B-fragment pair feeds 6 MFMAs: LDS reads 864/block (r7 was 1728).
// Per-output MFMA order identical to r4/r7 -> bitwise-identical numerics.
__global__ void __launch_bounds__(768, 6) step_kernel_p(
    const float* __restrict__ x,        // (B,T,H,W,C) fp32
    const uint4* __restrict__ Af,       // [9][6][2][64] uint4
    const float* __restrict__ bias4,    // [24][4]
    const uint4* __restrict__ g_in,     // h bf16 hi/lo planes (prev step)
    uint4* __restrict__ g_out,          // h bf16 hi/lo planes (this step)
    float* __restrict__ c_buf,          // (B,21,HW) fp32 in-place
    const float* __restrict__ mask,     // (H,W,1)
    float* __restrict__ out,            // (B,H,W,21) fp32, last step only
    int t, int first, int last) {
  __shared__ uint4 tileQ[NPOS * 8];     // 43520 B -> 2 blocks/CU
  unsigned char* tile = (unsigned char*)tileQ;
  unsigned short* bh16 = (unsigned short*)tileQ;   // epilogue bounce hi: [256][24]
  unsigned short* bl16 = bh16 + 256 * 24;          // bounce lo (offset 12288 B)

  int b   = blockIdx.z;
  int by0 = blockIdx.y * TSY;
  int bx0 = blockIdx.x * TSX;
  int tid = threadIdx.x;

  // ---- stage tile: h groups are raw 16B copies; x converted on the fly ----
  for (int i = tid; i < 7 * NPOS; i += 768) {
    int slot = i / NPOS;              // 0..5: h groups (g*2+hl); 6: x
    int pos  = i - slot * NPOS;
    int py = pos / TPX, px = pos - py * TPX;
    int gy = by0 - 1 + py, gx = bx0 - 1 + px;
    bool inb = (unsigned)gy < (unsigned)H_ && (unsigned)gx < (unsigned)W_;
    int sw = pos & 7;
    if (slot < 6) {
      int g = slot >> 1, hl = slot & 1;
      uint4 v = {0u, 0u, 0u, 0u};
      if (!first && inb)
        v = g_in[(size_t)hl * GH_LO + (size_t)(b * 3 + g) * HW_ + gy * W_ + gx];
      *(uint4*)&tile[pos * ROWB + ((slot ^ sw) * 16)] = v;
    } else {
      float x0 = 0.f, x1 = 0.f, x2 = 0.f;
      if (inb) {
        const float* xp = x + (((size_t)(b * T_ + t) * H_ + gy) * W_ + gx) * C_;
        x0 = xp[0]; x1 = xp[1]; x2 = xp[2];
      }
      unsigned short h0, h1, h2, l0, l1, l2;
      bsplit(x0, h0, l0); bsplit(x1, h1, l1); bsplit(x2, h2, l2);
      uint4 vh = {(unsigned)h0 | ((unsigned)h1 << 16), (unsigned)h2, 0u, 0u};
      uint4 vl = {(unsigned)l0 | ((unsigned)l1 << 16), (unsigned)l2, 0u, 0u};
      *(uint4*)&tile[pos * ROWB + ((6 ^ sw) * 16)] = vh;
      *(uint4*)&tile[pos * ROWB + ((7 ^ sw) * 16)] = vl;
    }
  }
  __syncthreads();

  int lane = tid & 63;
  int wv   = tid >> 6;     // 0..11
  int wvm  = wv >> 2;      // m-group 0..2 -> m-tiles {2wvm, 2wvm+1}
  int wvn  = wv & 3;       // row pair 0..3 -> rows {2wvn, 2wvn+1}
  int ln15 = lane & 15;
  int lg   = lane >> 4;

  f32x4 acc[2][4];
#pragma unroll
  for (int mt = 0; mt < 2; ++mt)
#pragma unroll
    for (int nt = 0; nt < 4; ++nt)
      acc[mt][nt] = (f32x4){0.f, 0.f, 0.f, 0.f};

#pragma unroll 1
  for (int tap = 0; tap < NTAP; ++tap) {
    int ky = tap / 3;
    int kx = tap - 3 * ky;

    const uint4* ap0 = Af + (size_t)((tap * MT_ + wvm * 2 + 0) * 2) * 64 + lane;
    const uint4* ap1 = Af + (size_t)((tap * MT_ + wvm * 2 + 1) * 2) * 64 + lane;
    bf16x8 ah0 = __builtin_bit_cast(bf16x8, ap0[0]);
    bf16x8 al0 = __builtin_bit_cast(bf16x8, ap0[64]);
    bf16x8 ah1 = __builtin_bit_cast(bf16x8, ap1[0]);
    bf16x8 al1 = __builtin_bit_cast(bf16x8, ap1[64]);

#pragma unroll
    for (int nt = 0; nt < 4; ++nt) {
      int pos = (wvn * 2 + (nt >> 1) + ky) * TPX + (nt & 1) * 16 + ln15 + kx;
      int sw  = pos & 7;
      uint4 hv = *(const uint4*)&tile[pos * ROWB + (((lg * 2 + 0) ^ sw) * 16)];
      uint4 lv = *(const uint4*)&tile[pos * ROWB + (((lg * 2 + 1) ^ sw) * 16)];
      bf16x8 bh = __builtin_bit_cast(bf16x8, hv);
      bf16x8 bl = __builtin_bit_cast(bf16x8, lv);
      acc[0][nt] = __builtin_amdgcn_mfma_f32_16x16x32_bf16(ah0, bh, acc[0][nt], 0, 0, 0);
      acc[0][nt] = __builtin_amdgcn_mfma_f32_16x16x32_bf16(ah0, bl, acc[0][nt], 0, 0, 0);
      acc[0][nt] = __builtin_amdgcn_mfma_f32_16x16x32_bf16(al0, bh, acc[0][nt], 0, 0, 0);
      acc[1][nt] = __builtin_amdgcn_mfma_f32_16x16x32_bf16(ah1, bh, acc[1][nt], 0, 0, 0);
      acc[1][nt] = __builtin_amdgcn_mfma_f32_16x16x32_bf16(ah1, bl, acc[1][nt], 0, 0, 0);
      acc[1][nt] = __builtin_amdgcn_mfma_f32_16x16x32_bf16(al1, bh, acc[1][nt], 0, 0, 0);
    }
  }

  __syncthreads();   // tile consumed by all waves; reuse LDS as epilogue bounce

  // ---- lane-local LSTM epilogue; h -> bounce LDS as split bf16 ----
#pragma unroll
  for (int mt = 0; mt < 2; ++mt) {
    int f = (wvm * 2 + mt) * 4 + lg;    // 0..23 (21..23 -> finite junk, zero-weighted)
    float4 bb = ((const float4*)bias4)[f];
#pragma unroll
    for (int nt = 0; nt < 4; ++nt) {
      int py = wvn * 2 + (nt >> 1);
      int px = (nt & 1) * 16 + ln15;
      int gy = by0 + py, gx = bx0 + px;
      if (gy < H_ && gx < W_) {
        int    pixL = py * TSX + px;
        size_t gpix = (size_t)gy * W_ + gx;
        float zi = acc[mt][nt][0] + bb.x;
        float zf = acc[mt][nt][1] + bb.y;
        float zc = acc[mt][nt][2] + bb.z;
        float zo = acc[mt][nt][3] + bb.w;
        float ig = hsig(zi);
        float fg = hsig(zf);
        float gg = fast_tanh(zc);
        float og = hsig(zo);
        float cp = (first || f >= F_) ? 0.0f
                                      : c_buf[((size_t)b * F_ + f) * HW_ + gpix];
        float cn = fg * cp + ig * gg;
        float hn = og * fast_tanh(cn);
        if (f < F_ && !last) c_buf[((size_t)b * F_ + f) * HW_ + gpix] = cn;
        if (last) {
          if (f < F_)
            out[((size_t)(b * H_ + gy) * W_ + gx) * F_ + f] = hn * mask[gpix];
        } else {
          unsigned short hh, hlw;
          bsplit(hn, hh, hlw);
          bh16[pixL * 24 + f] = hh;
          bl16[pixL * 24 + f] = hlw;
        }
      }
    }
  }

  if (last) return;
  __syncthreads();

  // ---- pack bounce -> g_out (coalesced 16B stores) ----
  for (int i = tid; i < 256 * 3 * 2; i += 768) {
    int hl   = (i >= 768) ? 1 : 0;
    int j    = i - hl * 768;
    int g    = j >> 8;
    int pixL = j & 255;
    int py = pixL >> 5, px = pixL & 31;
    int gy = by0 + py, gx = bx0 + px;
    if (gy < H_ && gx < W_) {
      const unsigned short* src = (hl ? bl16 : bh16) + pixL * 24 + g * 8;
      uint4 v = *(const uint4*)src;
      g_out[(size_t)hl * GH_LO + (size_t)(b * 3 + g) * HW_ + (size_t)gy * W_ + gx] = v;
    }
  }
}

// ---------------- fallback path (round-2 proven kernel, ~78 MB ws) ----------------
__global__ void __launch_bounds__(256, 3) step_kernel_f(
    const float* __restrict__ x,
    const uint4* __restrict__ Af,
    const float* __restrict__ bias4,
    const float* __restrict__ h_in,     // (B,F,HW) fp32
    float* __restrict__ h_out,          // (B,F,HW) fp32
    float* __restrict__ c_buf,
    const float* __restrict__ mask,
    float* __restrict__ out,
    int t, int first, int last) {
  __shared__ uint4 tileQ[NPOS * 8];
  unsigned char* tile = (unsigned char*)tileQ;

  int b   = blockIdx.z;
  int by0 = blockIdx.y * TSY;
  int bx0 = blockIdx.x * TSX;
  int tid = threadIdx.x;

  for (int i = tid; i < 32 * NPOS; i += 256) {
    int ci  = i / NPOS;
    int pos = i - ci * NPOS;
    int py = pos / TPX, px = pos - py * TPX;
    int gy = by0 - 1 + py, gx = bx0 - 1 + px;
    float v = 0.0f;
    if ((unsigned)gy < (unsigned)H_ && (unsigned)gx < (unsigned)W_) {
      if (ci < F_) {
        if (!first) v = h_in[(size_t)(b * F_ + ci) * HW_ + gy * W_ + gx];
      } else if (ci >= 24 && ci < 27) {
        v = x[(((size_t)(b * T_ + t) * H_ + gy) * W_ + gx) * C_ + (ci - 24)];
      }
    }
    unsigned short hb, lb;
    bsplit(v, hb, lb);
    int g  = ci >> 3, e = ci & 7, sw = pos & 7;
    *(unsigned short*)&tile[pos * ROWB + (((g * 2 + 0) ^ sw) * 16) + e * 2] = hb;
    *(unsigned short*)&tile[pos * ROWB + (((g * 2 + 1) ^ sw) * 16) + e * 2] = lb;
  }
  __syncthreads();

  int lane = tid & 63;
  int wv   = tid >> 6;
  int ln15 = lane & 15;
  int lg   = lane >> 4;

  f32x4 acc[MT_][4];
#pragma unroll
  for (int mt = 0; mt < MT_; ++mt)
#pragma unroll
    for (int nt = 0; nt < 4; ++nt)
      acc[mt][nt] = (f32x4){0.f, 0.f, 0.f, 0.f};

#pragma unroll 1
  for (int tap = 0; tap < NTAP; ++tap) {
    int ky = tap / 3;
    int kx = tap - 3 * ky;

    bf16x8 bh[4], bl[4];
#pragma unroll
    for (int nt = 0; nt < 4; ++nt) {
      int pos = (wv * 2 + (nt >> 1) + ky) * TPX + (nt & 1) * 16 + ln15 + kx;
      int sw  = pos & 7;
      uint4 hv = *(const uint4*)&tile[pos * ROWB + (((lg * 2 + 0) ^ sw) * 16)];
      uint4 lv = *(const uint4*)&tile[pos * ROWB + (((lg * 2 + 1) ^ sw) * 16)];
      bh[nt] = __builtin_bit_cast(bf16x8, hv);
      bl[nt] = __builtin_bit_cast(bf16x8, lv);
    }

#pragma unroll
    for (int mt = 0; mt < MT_; ++mt) {
      const uint4* ap = Af + (size_t)((tap * MT_ + mt) * 2) * 64 + lane;
      bf16x8 ah = __builtin_bit_cast(bf16x8, ap[0]);
      bf16x8 al = __builtin_bit_cast(bf16x8, ap[64]);
#pragma unroll
      for (int nt = 0; nt < 4; ++nt) {
        acc[mt][nt] = __builtin_amdgcn_mfma_f32_16x16x32_bf16(ah, bh[nt], acc[mt][nt], 0, 0, 0);
        acc[mt][nt] = __builtin_amdgcn_mfma_f32_16x16x32_bf16(ah, bl[nt], acc[mt][nt], 0, 0, 0);
        acc[mt][nt] = __builtin_amdgcn_mfma_f32_16x16x32_bf16(al, bh[nt], acc[mt][nt], 0, 0, 0);
      }
    }
  }

#pragma unroll
  for (int mt = 0; mt < MT_; ++mt) {
    int f = mt * 4 + lg;
    if (f < F_) {
      float4 bb = ((const float4*)bias4)[f];
#pragma unroll
      for (int nt = 0; nt < 4; ++nt) {
        int gy = by0 + wv * 2 + (nt >> 1);
        int gx = bx0 + (nt & 1) * 16 + ln15;
        if (gy < H_ && gx < W_) {
          size_t idx = ((size_t)b * F_ + f) * HW_ + (size_t)gy * W_ + gx;
          float zi = acc[mt][nt][0] + bb.x;
          float zf = acc[mt][nt][1] + bb.y;
          float zc = acc[mt][nt][2] + bb.z;
          float zo = acc[mt][nt][3] + bb.w;
          float ig = hsig(zi);
          float fg = hsig(zf);
          float gg = fast_tanh(zc);
          float og = hsig(zo);
          float cp = first ? 0.0f : c_buf[idx];
          float cn = fg * cp + ig * gg;
          float hn = og * fast_tanh(cn);
          c_buf[idx] = cn;
          if (!last) h_out[idx] = hn;
          else {
            out[((size_t)(b * H_ + gy) * W_ + gx) * F_ + f] =
                hn * mask[(size_t)gy * W_ + gx];
          }
        }
      }
    }
  }
}

extern "C" void kernel_launch(void* const* d_in, const int* in_sizes, int n_in,
                              void* d_out, int out_size, void* d_ws, size_t ws_size,
                              hipStream_t stream) {
  const float* x  = (const float*)d_in[0];
  const float* k  = (const float*)d_in[1];
  const float* rk = (const float*)d_in[2];
  const float* bs = (const float*)d_in[3];
  const float* mk = (const float*)d_in[4];
  float* outF = (float*)d_out;

  char* ws = (char*)d_ws;
  unsigned short* Af = (unsigned short*)ws;          // 110592 B
  float* bias4 = (float*)(ws + 110592);              // 384 B
  size_t off = (size_t)((110592 + 384 + 255) & ~255);
  size_t HWF = (size_t)B_ * H_ * W_ * F_;

  prep_kernel<<<dim3((NTAP * MT_ * 2 * 64 * 8 + 255) / 256), 256, 0, stream>>>(
      k, rk, bs, Af, bias4);

  dim3 grid((W_ + TSX - 1) / TSX, (H_ + TSY - 1) / TSY, B_);  // (6, 21, 16)

  size_t need_packed = off + (size_t)4 * GH_LO * 16 + HWF * 4;  // ~128.8 MB

  if (ws_size >= need_packed) {
    // packed-h path: ghA/ghB = split-bf16 h planes, c fp32
    uint4* ghA = (uint4*)(ws + off);
    uint4* ghB = ghA + 2 * GH_LO;
    float* cB  = (float*)(ghB + 2 * GH_LO);
    for (int t = 0; t < T_; ++t) {
      const uint4* gin = (t & 1) ? ghB : ghA;
      uint4* gout      = (t & 1) ? ghA : ghB;
      step_kernel_p<<<grid, 768, 0, stream>>>(x, (const uint4*)Af, bias4, gin, gout,
                                              cB, mk, outF, t,
                                              (t == 0) ? 1 : 0, (t == T_ - 1) ? 1 : 0);
    }
  } else {
    // fallback (round-2 proven): fp32 h ping-pong via ws + outF, ~78.4 MB
    float* hA = (float*)(ws + off);
    float* cB = hA + HWF;
    for (int t = 0; t < T_; ++t) {
      const float* hi = (t & 1) ? hA : outF;
      float* ho       = (t & 1) ? outF : hA;
      step_kernel_f<<<grid, 256, 0, stream>>>(x, (const uint4*)Af, bias4, hi, ho,
                                              cB, mk, outF, t,
                                              (t == 0) ? 1 : 0, (t == T_ - 1) ? 1 : 0);
    }
  }
}

// Round 9
// 1201.904 us; speedup vs baseline: 1.4588x; 1.2655x over previous
//
#include <hip/hip_runtime.h>

// Problem constants
#define B_   16
#define T_   16
#define H_   161
#define W_   181
#define HW_  (H_*W_)     // 29141
#define C_   3
#define F_   21
#define F4_  84
#define TSX  32          // tile width
#define TSY  8           // tile height (256 px per block)
#define TPX  34          // tile + halo
#define TPY  10
#define NPOS (TPX*TPY)   // 340
#define NTAP 9
#define MT_  6           // m-tiles of 16 -> 96 gate rows (m = f*4+gate)
#define ROWB4 64         // packed kernel: 4 slots x 16B per position (hi-only B)
#define ROWBF 128        // fallback kernel: 8 slots x 16B (hi/lo B)
// ci map: 0..20 = h (bf16-hi), 21..23 = pad, 24..26 = x_hi, 27..29 = x_lo, 30..31 = pad.
// A weights: ci 27..29 carry wx duplicated (both hi and lo fragments) so the
// x path is EXACT: (wx_hi+wx_lo)*(x_hi+x_lo). Only h is truncated to bf16 (2^-9).
#define GH_ ((size_t)B_ * 3 * HW_)   // uint4 elements per gh buffer (hi plane only)

typedef short bf16x8 __attribute__((ext_vector_type(8)));
typedef float f32x4  __attribute__((ext_vector_type(4)));

__device__ __forceinline__ float hsig(float x) {
  return fminf(fmaxf(0.2f * x + 0.5f, 0.0f), 1.0f);
}

__device__ __forceinline__ float fast_tanh(float x) {
  float ax = fabsf(x);
  float t = __expf(-2.0f * ax);
  float r = (1.0f - t) * __builtin_amdgcn_rcpf(1.0f + t);
  return copysignf(r, x);
}

// round-to-nearest-even fp32 -> bf16 bits
__device__ __forceinline__ unsigned short bf16r(float x) {
  unsigned u = __float_as_uint(x);
  return (unsigned short)((u + 0x7FFFu + ((u >> 16) & 1u)) >> 16);
}
__device__ __forceinline__ void bsplit(float v, unsigned short& hi, unsigned short& lo) {
  hi = bf16r(v);
  float hf = __uint_as_float((unsigned)hi << 16);
  lo = bf16r(v - hf);
}

// A-fragment pack: Af[tap][mt][hl][lane] (uint4 = 8 bf16). HW-verified r2.
// mfma_f32_16x16x32_bf16 A layout: row m = lane&15, k = (lane>>4)*8 + j.
// m = f*4 + gate; oc = gate*21 + f (Keras i,f,c,o).
// hl=0: bf16(w); hl=1: bf16(w - bf16(w)). x weights duplicated at ci 27..29.
__global__ void prep_kernel(const float* __restrict__ k,
                            const float* __restrict__ rk,
                            const float* __restrict__ bias,
                            unsigned short* __restrict__ Af,
                            float* __restrict__ bias4) {
  int i = blockIdx.x * 256 + threadIdx.x;
  if (i < NTAP * MT_ * 2 * 64 * 8) {
    int j    = i & 7;
    int lane = (i >> 3) & 63;
    int hl   = (i >> 9) & 1;
    int mtp  = i >> 10;          // tap*MT_ + mt
    int mt   = mtp % MT_;
    int tap  = mtp / MT_;
    int m    = mt * 16 + (lane & 15);
    int ci   = (lane >> 4) * 8 + j;
    int f    = m >> 2, gate = m & 3;
    float w = 0.0f;
    if (f < F_) {
      int oc = gate * F_ + f;
      if (ci < F_)                  w = rk[(tap * F_ + ci) * F4_ + oc];        // h
      else if (ci >= 24 && ci < 27) w = k[(tap * C_ + (ci - 24)) * F4_ + oc];  // x_hi slot
      else if (ci >= 27 && ci < 30) w = k[(tap * C_ + (ci - 27)) * F4_ + oc];  // x_lo slot (dup wx)
    }
    unsigned short hb = bf16r(w);
    unsigned short outv;
    if (hl == 0) outv = hb;
    else {
      float hf = __uint_as_float((unsigned)hb << 16);
      outv = bf16r(w - hf);
    }
    Af[i] = outv;
  }
  if (i < 96) {   // bias4[f][gate], f padded to 24
    int f = i >> 2, gate = i & 3;
    bias4[i] = (f < F_) ? bias[gate * F_ + f] : 0.0f;
  }
}

// ---------------- packed-h 1-step kernel (hi-only B) ----------------
// grid (6,21,16), block 768 (12 waves): wvm = wv>>2 (0..2) owns m-tiles
// {2wvm,2wvm+1}; wvn = wv&3 owns rows {2wvn,2wvn+1} (4 n-tiles).
// Per (tap,nt): ONE ds_read_b128 (bh) feeds 4 MFMAs (ah0,al0,ah1,al1 x bh).
// B reads 36/wave (r8: 72); MFMAs 144/wave (r8: 216); LDS tile 21.8 KB.
// h exchanged between steps as bf16-hi plane only (gh single plane).
__global__ void __launch_bounds__(768, 6) step_kernel_p(
    const float* __restrict__ x,        // (B,T,H,W,C) fp32
    const uint4* __restrict__ Af,       // [9][6][2][64] uint4
    const float* __restrict__ bias4,    // [24][4]
    const uint4* __restrict__ g_in,     // h bf16-hi plane (prev step)
    uint4* __restrict__ g_out,          // h bf16-hi plane (this step)
    float* __restrict__ c_buf,          // (B,21,HW) fp32 in-place
    const float* __restrict__ mask,     // (H,W,1)
    float* __restrict__ out,            // (B,H,W,21) fp32, last step only
    int t, int first, int last) {
  __shared__ uint4 tileQ[NPOS * 4];     // 21760 B
  unsigned char* tile = (unsigned char*)tileQ;
  unsigned short* bh16 = (unsigned short*)tileQ;   // epilogue bounce: [256][24] (12288 B)

  int b   = blockIdx.z;
  int by0 = blockIdx.y * TSY;
  int bx0 = blockIdx.x * TSX;
  int tid = threadIdx.x;

  // ---- stage tile: slots 0..2 = h groups (raw 16B copies); slot 3 = x hi+lo ----
  for (int i = tid; i < 4 * NPOS; i += 768) {
    int slot = i / NPOS;
    int pos  = i - slot * NPOS;
    int py = pos / TPX, px = pos - py * TPX;
    int gy = by0 - 1 + py, gx = bx0 - 1 + px;
    bool inb = (unsigned)gy < (unsigned)H_ && (unsigned)gx < (unsigned)W_;
    int sw = pos & 3;
    if (slot < 3) {
      uint4 v = {0u, 0u, 0u, 0u};
      if (!first && inb)
        v = g_in[(size_t)(b * 3 + slot) * HW_ + gy * W_ + gx];
      *(uint4*)&tile[pos * ROWB4 + ((slot ^ sw) * 16)] = v;
    } else {
      float x0 = 0.f, x1 = 0.f, x2 = 0.f;
      if (inb) {
        const float* xp = x + (((size_t)(b * T_ + t) * H_ + gy) * W_ + gx) * C_;
        x0 = xp[0]; x1 = xp[1]; x2 = xp[2];
      }
      unsigned short h0, h1, h2, l0, l1, l2;
      bsplit(x0, h0, l0); bsplit(x1, h1, l1); bsplit(x2, h2, l2);
      // k-slots 24..31 within this 16B: [x0h,x1h,x2h, x0l,x1l,x2l, 0,0]
      uint4 v;
      v.x = (unsigned)h0 | ((unsigned)h1 << 16);
      v.y = (unsigned)h2 | ((unsigned)l0 << 16);
      v.z = (unsigned)l1 | ((unsigned)l2 << 16);
      v.w = 0u;
      *(uint4*)&tile[pos * ROWB4 + ((3 ^ sw) * 16)] = v;
    }
  }
  __syncthreads();

  int lane = tid & 63;
  int wv   = tid >> 6;     // 0..11
  int wvm  = wv >> 2;      // m-group 0..2 -> m-tiles {2wvm, 2wvm+1}
  int wvn  = wv & 3;       // row pair 0..3 -> rows {2wvn, 2wvn+1}
  int ln15 = lane & 15;
  int lg   = lane >> 4;

  f32x4 acc[2][4];
#pragma unroll
  for (int mt = 0; mt < 2; ++mt)
#pragma unroll
    for (int nt = 0; nt < 4; ++nt)
      acc[mt][nt] = (f32x4){0.f, 0.f, 0.f, 0.f};

#pragma unroll 1
  for (int tap = 0; tap < NTAP; ++tap) {
    int ky = tap / 3;
    int kx = tap - 3 * ky;

    const uint4* ap0 = Af + (size_t)((tap * MT_ + wvm * 2 + 0) * 2) * 64 + lane;
    const uint4* ap1 = Af + (size_t)((tap * MT_ + wvm * 2 + 1) * 2) * 64 + lane;
    bf16x8 ah0 = __builtin_bit_cast(bf16x8, ap0[0]);
    bf16x8 al0 = __builtin_bit_cast(bf16x8, ap0[64]);
    bf16x8 ah1 = __builtin_bit_cast(bf16x8, ap1[0]);
    bf16x8 al1 = __builtin_bit_cast(bf16x8, ap1[64]);

#pragma unroll
    for (int nt = 0; nt < 4; ++nt) {
      int pos = (wvn * 2 + (nt >> 1) + ky) * TPX + (nt & 1) * 16 + ln15 + kx;
      int sw  = pos & 3;
      uint4 hv = *(const uint4*)&tile[pos * ROWB4 + ((lg ^ sw) * 16)];
      bf16x8 bh = __builtin_bit_cast(bf16x8, hv);
      acc[0][nt] = __builtin_amdgcn_mfma_f32_16x16x32_bf16(ah0, bh, acc[0][nt], 0, 0, 0);
      acc[0][nt] = __builtin_amdgcn_mfma_f32_16x16x32_bf16(al0, bh, acc[0][nt], 0, 0, 0);
      acc[1][nt] = __builtin_amdgcn_mfma_f32_16x16x32_bf16(ah1, bh, acc[1][nt], 0, 0, 0);
      acc[1][nt] = __builtin_amdgcn_mfma_f32_16x16x32_bf16(al1, bh, acc[1][nt], 0, 0, 0);
    }
  }

  __syncthreads();   // tile consumed by all waves; reuse LDS as epilogue bounce

  // ---- lane-local LSTM epilogue; h -> bounce LDS as bf16-hi ----
#pragma unroll
  for (int mt = 0; mt < 2; ++mt) {
    int f = (wvm * 2 + mt) * 4 + lg;    // 0..23 (21..23 -> exact zero h)
    float4 bb = ((const float4*)bias4)[f];
#pragma unroll
    for (int nt = 0; nt < 4; ++nt) {
      int py = wvn * 2 + (nt >> 1);
      int px = (nt & 1) * 16 + ln15;
      int gy = by0 + py, gx = bx0 + px;
      if (gy < H_ && gx < W_) {
        int    pixL = py * TSX + px;
        size_t gpix = (size_t)gy * W_ + gx;
        float zi = acc[mt][nt][0] + bb.x;
        float zf = acc[mt][nt][1] + bb.y;
        float zc = acc[mt][nt][2] + bb.z;
        float zo = acc[mt][nt][3] + bb.w;
        float ig = hsig(zi);
        float fg = hsig(zf);
        float gg = fast_tanh(zc);
        float og = hsig(zo);
        float cp = (first || f >= F_) ? 0.0f
                                      : c_buf[((size_t)b * F_ + f) * HW_ + gpix];
        float cn = fg * cp + ig * gg;
        float hn = og * fast_tanh(cn);
        if (f < F_ && !last) c_buf[((size_t)b * F_ + f) * HW_ + gpix] = cn;
        if (last) {
          if (f < F_)
            out[((size_t)(b * H_ + gy) * W_ + gx) * F_ + f] = hn * mask[gpix];
        } else {
          bh16[pixL * 24 + f] = bf16r(hn);
        }
      }
    }
  }

  if (last) return;
  __syncthreads();

  // ---- pack bounce -> g_out (coalesced 16B stores), 1 iter/thread ----
  for (int i = tid; i < 256 * 3; i += 768) {
    int g    = i >> 8;
    int pixL = i & 255;
    int py = pixL >> 5, px = pixL & 31;
    int gy = by0 + py, gx = bx0 + px;
    if (gy < H_ && gx < W_) {
      uint4 v = *(const uint4*)(bh16 + pixL * 24 + g * 8);
      g_out[(size_t)(b * 3 + g) * HW_ + (size_t)gy * W_ + gx] = v;
    }
  }
}

// ---------------- fallback path (round-2 proven structure, ~78 MB ws) ----------------
// Consumes the same Af (x_lo k-slots stage as zero; its ah*bl term recovers x_lo).
__global__ void __launch_bounds__(256, 3) step_kernel_f(
    const float* __restrict__ x,
    const uint4* __restrict__ Af,
    const float* __restrict__ bias4,
    const float* __restrict__ h_in,     // (B,F,HW) fp32
    float* __restrict__ h_out,          // (B,F,HW) fp32
    float* __restrict__ c_buf,
    const float* __restrict__ mask,
    float* __restrict__ out,
    int t, int first, int last) {
  __shared__ uint4 tileQ[NPOS * 8];
  unsigned char* tile = (unsigned char*)tileQ;

  int b   = blockIdx.z;
  int by0 = blockIdx.y * TSY;
  int bx0 = blockIdx.x * TSX;
  int tid = threadIdx.x;

  for (int i = tid; i < 32 * NPOS; i += 256) {
    int ci  = i / NPOS;
    int pos = i - ci * NPOS;
    int py = pos / TPX, px = pos - py * TPX;
    int gy = by0 - 1 + py, gx = bx0 - 1 + px;
    float v = 0.0f;
    if ((unsigned)gy < (unsigned)H_ && (unsigned)gx < (unsigned)W_) {
      if (ci < F_) {
        if (!first) v = h_in[(size_t)(b * F_ + ci) * HW_ + gy * W_ + gx];
      } else if (ci >= 24 && ci < 27) {
        v = x[(((size_t)(b * T_ + t) * H_ + gy) * W_ + gx) * C_ + (ci - 24)];
      }
    }
    unsigned short hb, lb;
    bsplit(v, hb, lb);
    int g  = ci >> 3, e = ci & 7, sw = pos & 7;
    *(unsigned short*)&tile[pos * ROWBF + (((g * 2 + 0) ^ sw) * 16) + e * 2] = hb;
    *(unsigned short*)&tile[pos * ROWBF + (((g * 2 + 1) ^ sw) * 16) + e * 2] = lb;
  }
  __syncthreads();

  int lane = tid & 63;
  int wv   = tid >> 6;
  int ln15 = lane & 15;
  int lg   = lane >> 4;

  f32x4 acc[MT_][4];
#pragma unroll
  for (int mt = 0; mt < MT_; ++mt)
#pragma unroll
    for (int nt = 0; nt < 4; ++nt)
      acc[mt][nt] = (f32x4){0.f, 0.f, 0.f, 0.f};

#pragma unroll 1
  for (int tap = 0; tap < NTAP; ++tap) {
    int ky = tap / 3;
    int kx = tap - 3 * ky;

    bf16x8 bh[4], bl[4];
#pragma unroll
    for (int nt = 0; nt < 4; ++nt) {
      int pos = (wv * 2 + (nt >> 1) + ky) * TPX + (nt & 1) * 16 + ln15 + kx;
      int sw  = pos & 7;
      uint4 hv = *(const uint4*)&tile[pos * ROWBF + (((lg * 2 + 0) ^ sw) * 16)];
      uint4 lv = *(const uint4*)&tile[pos * ROWBF + (((lg * 2 + 1) ^ sw) * 16)];
      bh[nt] = __builtin_bit_cast(bf16x8, hv);
      bl[nt] = __builtin_bit_cast(bf16x8, lv);
    }

#pragma unroll
    for (int mt = 0; mt < MT_; ++mt) {
      const uint4* ap = Af + (size_t)((tap * MT_ + mt) * 2) * 64 + lane;
      bf16x8 ah = __builtin_bit_cast(bf16x8, ap[0]);
      bf16x8 al = __builtin_bit_cast(bf16x8, ap[64]);
#pragma unroll
      for (int nt = 0; nt < 4; ++nt) {
        acc[mt][nt] = __builtin_amdgcn_mfma_f32_16x16x32_bf16(ah, bh[nt], acc[mt][nt], 0, 0, 0);
        acc[mt][nt] = __builtin_amdgcn_mfma_f32_16x16x32_bf16(ah, bl[nt], acc[mt][nt], 0, 0, 0);
        acc[mt][nt] = __builtin_amdgcn_mfma_f32_16x16x32_bf16(al, bh[nt], acc[mt][nt], 0, 0, 0);
      }
    }
  }

#pragma unroll
  for (int mt = 0; mt < MT_; ++mt) {
    int f = mt * 4 + lg;
    if (f < F_) {
      float4 bb = ((const float4*)bias4)[f];
#pragma unroll
      for (int nt = 0; nt < 4; ++nt) {
        int gy = by0 + wv * 2 + (nt >> 1);
        int gx = bx0 + (nt & 1) * 16 + ln15;
        if (gy < H_ && gx < W_) {
          size_t idx = ((size_t)b * F_ + f) * HW_ + (size_t)gy * W_ + gx;
          float zi = acc[mt][nt][0] + bb.x;
          float zf = acc[mt][nt][1] + bb.y;
          float zc = acc[mt][nt][2] + bb.z;
          float zo = acc[mt][nt][3] + bb.w;
          float ig = hsig(zi);
          float fg = hsig(zf);
          float gg = fast_tanh(zc);
          float og = hsig(zo);
          float cp = first ? 0.0f : c_buf[idx];
          float cn = fg * cp + ig * gg;
          float hn = og * fast_tanh(cn);
          c_buf[idx] = cn;
          if (!last) h_out[idx] = hn;
          else {
            out[((size_t)(b * H_ + gy) * W_ + gx) * F_ + f] =
                hn * mask[(size_t)gy * W_ + gx];
          }
        }
      }
    }
  }
}

extern "C" void kernel_launch(void* const* d_in, const int* in_sizes, int n_in,
                              void* d_out, int out_size, void* d_ws, size_t ws_size,
                              hipStream_t stream) {
  const float* x  = (const float*)d_in[0];
  const float* k  = (const float*)d_in[1];
  const float* rk = (const float*)d_in[2];
  const float* bs = (const float*)d_in[3];
  const float* mk = (const float*)d_in[4];
  float* outF = (float*)d_out;

  char* ws = (char*)d_ws;
  unsigned short* Af = (unsigned short*)ws;          // 110592 B
  float* bias4 = (float*)(ws + 110592);              // 384 B
  size_t off = (size_t)((110592 + 384 + 255) & ~255);
  size_t HWF = (size_t)B_ * H_ * W_ * F_;

  prep_kernel<<<dim3((NTAP * MT_ * 2 * 64 * 8 + 255) / 256), 256, 0, stream>>>(
      k, rk, bs, Af, bias4);

  dim3 grid((W_ + TSX - 1) / TSX, (H_ + TSY - 1) / TSY, B_);  // (6, 21, 16)

  size_t need_packed = off + (size_t)2 * GH_ * 16 + HWF * 4;  // ~84 MB

  if (ws_size >= need_packed) {
    // packed-h path: ghA/ghB = bf16-hi h planes, c fp32
    uint4* ghA = (uint4*)(ws + off);
    uint4* ghB = ghA + GH_;
    float* cB  = (float*)(ghB + GH_);
    for (int t = 0; t < T_; ++t) {
      const uint4* gin = (t & 1) ? ghB : ghA;
      uint4* gout      = (t & 1) ? ghA : ghB;
      step_kernel_p<<<grid, 768, 0, stream>>>(x, (const uint4*)Af, bias4, gin, gout,
                                              cB, mk, outF, t,
                                              (t == 0) ? 1 : 0, (t == T_ - 1) ? 1 : 0);
    }
  } else {
    // fallback (round-2 proven): fp32 h ping-pong via ws + outF, ~78.4 MB
    float* hA = (float*)(ws + off);
    float* cB = hA + HWF;
    for (int t = 0; t < T_; ++t) {
      const float* hi = (t & 1) ? hA : outF;
      float* ho       = (t & 1) ? outF : hA;
      step_kernel_f<<<grid, 256, 0, stream>>>(x, (const uint4*)Af, bias4, hi, ho,
                                              cB, mk, outF, t,
                                              (t == 0) ? 1 : 0, (t == T_ - 1) ? 1 : 0);
    }
  }
}

// Round 10
// 1181.930 us; speedup vs baseline: 1.4834x; 1.0169x over previous
//
#include <hip/hip_runtime.h>

// Problem constants
#define B_   16
#define T_   16
#define H_   161
#define W_   181
#define HW_  (H_*W_)     // 29141
#define C_   3
#define F_   21
#define F4_  84
#define TSX  32          // tile width
#define TSY  8           // tile height (256 px per block)
#define TPX  34          // tile + halo
#define TPY  10
#define NPOS (TPX*TPY)   // 340
#define NTAP 9
#define MT_  6           // m-tiles of 16 -> 96 gate rows (m = f*4+gate)
#define ROWB4 64         // packed kernel: 4 slots x 16B per position (hi-only B)
#define ROWBF 128        // fallback kernel: 8 slots x 16B (hi/lo B)
// ci map: 0..20 = h (bf16-hi), 21..23 = pad, 24..26 = x_hi, 27..29 = x_lo, 30..31 = pad.
// A weights: ci 27..29 carry wx duplicated (both hi and lo fragments) so the
// x path is EXACT: (wx_hi+wx_lo)*(x_hi+x_lo). Only h is truncated to bf16 (2^-9).
#define GH_ ((size_t)B_ * 3 * HW_)   // uint4 elements per gh buffer (hi plane only)

typedef short bf16x8 __attribute__((ext_vector_type(8)));
typedef float f32x4  __attribute__((ext_vector_type(4)));

__device__ __forceinline__ float hsig(float x) {
  return fminf(fmaxf(0.2f * x + 0.5f, 0.0f), 1.0f);
}

__device__ __forceinline__ float fast_tanh(float x) {
  float ax = fabsf(x);
  float t = __expf(-2.0f * ax);
  float r = (1.0f - t) * __builtin_amdgcn_rcpf(1.0f + t);
  return copysignf(r, x);
}

// round-to-nearest-even fp32 -> bf16 bits
__device__ __forceinline__ unsigned short bf16r(float x) {
  unsigned u = __float_as_uint(x);
  return (unsigned short)((u + 0x7FFFu + ((u >> 16) & 1u)) >> 16);
}
__device__ __forceinline__ void bsplit(float v, unsigned short& hi, unsigned short& lo) {
  hi = bf16r(v);
  float hf = __uint_as_float((unsigned)hi << 16);
  lo = bf16r(v - hf);
}

// A-fragment pack: Af[tap][mt][hl][lane] (uint4 = 8 bf16). HW-verified r2.
// mfma_f32_16x16x32_bf16 A layout: row m = lane&15, k = (lane>>4)*8 + j.
// m = f*4 + gate; oc = gate*21 + f (Keras i,f,c,o).
// hl=0: bf16(w); hl=1: bf16(w - bf16(w)). x weights duplicated at ci 27..29.
__global__ void prep_kernel(const float* __restrict__ k,
                            const float* __restrict__ rk,
                            const float* __restrict__ bias,
                            unsigned short* __restrict__ Af,
                            float* __restrict__ bias4) {
  int i = blockIdx.x * 256 + threadIdx.x;
  if (i < NTAP * MT_ * 2 * 64 * 8) {
    int j    = i & 7;
    int lane = (i >> 3) & 63;
    int hl   = (i >> 9) & 1;
    int mtp  = i >> 10;          // tap*MT_ + mt
    int mt   = mtp % MT_;
    int tap  = mtp / MT_;
    int m    = mt * 16 + (lane & 15);
    int ci   = (lane >> 4) * 8 + j;
    int f    = m >> 2, gate = m & 3;
    float w = 0.0f;
    if (f < F_) {
      int oc = gate * F_ + f;
      if (ci < F_)                  w = rk[(tap * F_ + ci) * F4_ + oc];        // h
      else if (ci >= 24 && ci < 27) w = k[(tap * C_ + (ci - 24)) * F4_ + oc];  // x_hi slot
      else if (ci >= 27 && ci < 30) w = k[(tap * C_ + (ci - 27)) * F4_ + oc];  // x_lo slot (dup wx)
    }
    unsigned short hb = bf16r(w);
    unsigned short outv;
    if (hl == 0) outv = hb;
    else {
      float hf = __uint_as_float((unsigned)hb << 16);
      outv = bf16r(w - hf);
    }
    Af[i] = outv;
  }
  if (i < 96) {   // bias4[f][gate], f padded to 24
    int f = i >> 2, gate = i & 3;
    bias4[i] = (f < F_) ? bias[gate * F_ + f] : 0.0f;
  }
}

// ---------------- packed-h 1-step kernel (hi-only B, de-lockstepped) ----------------
// grid (6,21,16), block 768 (12 waves): wvm = wv>>2 (0..2) owns m-tiles
// {2wvm,2wvm+1}; wvn = wv&3 owns rows {2wvn,2wvn+1} (4 n-tiles).
// Round 10: (1) bounce buffer DISJOINT from tile -> no barrier between MFMA
// and epilogue: waves de-lockstep, epilogue VALU/VMEM of early waves overlaps
// MFMA of late waves. (2) c_buf prefetched into 8 regs right after the stage
// barrier (budget 72+8=80 <= 85 cap) so c latency hides under MFMA.
__global__ void __launch_bounds__(768, 6) step_kernel_p(
    const float* __restrict__ x,        // (B,T,H,W,C) fp32
    const uint4* __restrict__ Af,       // [9][6][2][64] uint4
    const float* __restrict__ bias4,    // [24][4]
    const uint4* __restrict__ g_in,     // h bf16-hi plane (prev step)
    uint4* __restrict__ g_out,          // h bf16-hi plane (this step)
    float* __restrict__ c_buf,          // (B,21,HW) fp32 in-place
    const float* __restrict__ mask,     // (H,W,1)
    float* __restrict__ out,            // (B,H,W,21) fp32, last step only
    int t, int first, int last) {
  __shared__ uint4 tileQ[NPOS * 4];     // 21760 B
  __shared__ uint4 bounceQ[768];        // 12288 B (disjoint -> no post-MFMA barrier)
  unsigned char* tile = (unsigned char*)tileQ;
  unsigned short* bh16 = (unsigned short*)bounceQ;   // [256][24] bf16-hi bounce

  int b   = blockIdx.z;
  int by0 = blockIdx.y * TSY;
  int bx0 = blockIdx.x * TSX;
  int tid = threadIdx.x;

  // ---- stage tile: slots 0..2 = h groups (raw 16B copies); slot 3 = x hi+lo ----
  for (int i = tid; i < 4 * NPOS; i += 768) {
    int slot = i / NPOS;
    int pos  = i - slot * NPOS;
    int py = pos / TPX, px = pos - py * TPX;
    int gy = by0 - 1 + py, gx = bx0 - 1 + px;
    bool inb = (unsigned)gy < (unsigned)H_ && (unsigned)gx < (unsigned)W_;
    int sw = pos & 3;
    if (slot < 3) {
      uint4 v = {0u, 0u, 0u, 0u};
      if (!first && inb)
        v = g_in[(size_t)(b * 3 + slot) * HW_ + gy * W_ + gx];
      *(uint4*)&tile[pos * ROWB4 + ((slot ^ sw) * 16)] = v;
    } else {
      float x0 = 0.f, x1 = 0.f, x2 = 0.f;
      if (inb) {
        const float* xp = x + (((size_t)(b * T_ + t) * H_ + gy) * W_ + gx) * C_;
        x0 = xp[0]; x1 = xp[1]; x2 = xp[2];
      }
      unsigned short h0, h1, h2, l0, l1, l2;
      bsplit(x0, h0, l0); bsplit(x1, h1, l1); bsplit(x2, h2, l2);
      // k-slots 24..31 within this 16B: [x0h,x1h,x2h, x0l,x1l,x2l, 0,0]
      uint4 v;
      v.x = (unsigned)h0 | ((unsigned)h1 << 16);
      v.y = (unsigned)h2 | ((unsigned)l0 << 16);
      v.z = (unsigned)l1 | ((unsigned)l2 << 16);
      v.w = 0u;
      *(uint4*)&tile[pos * ROWB4 + ((3 ^ sw) * 16)] = v;
    }
  }
  __syncthreads();

  int lane = tid & 63;
  int wv   = tid >> 6;     // 0..11
  int wvm  = wv >> 2;      // m-group 0..2 -> m-tiles {2wvm, 2wvm+1}
  int wvn  = wv & 3;       // row pair 0..3 -> rows {2wvn, 2wvn+1}
  int ln15 = lane & 15;
  int lg   = lane >> 4;

  // ---- c prefetch (8 regs): issued after the barrier so the ~L2/HBM latency
  // overlaps the MFMA phase instead of trailing it. Budget 72+8=80 <= 85.
  float cpre[2][4];
#pragma unroll
  for (int mt = 0; mt < 2; ++mt) {
    int f = (wvm * 2 + mt) * 4 + lg;
#pragma unroll
    for (int nt = 0; nt < 4; ++nt) {
      int gy = by0 + wvn * 2 + (nt >> 1);
      int gx = bx0 + (nt & 1) * 16 + ln15;
      float cv = 0.0f;
      if (!first && f < F_ && gy < H_ && gx < W_)
        cv = c_buf[((size_t)b * F_ + f) * HW_ + (size_t)gy * W_ + gx];
      cpre[mt][nt] = cv;
    }
  }

  f32x4 acc[2][4];
#pragma unroll
  for (int mt = 0; mt < 2; ++mt)
#pragma unroll
    for (int nt = 0; nt < 4; ++nt)
      acc[mt][nt] = (f32x4){0.f, 0.f, 0.f, 0.f};

#pragma unroll 1
  for (int tap = 0; tap < NTAP; ++tap) {
    int ky = tap / 3;
    int kx = tap - 3 * ky;

    const uint4* ap0 = Af + (size_t)((tap * MT_ + wvm * 2 + 0) * 2) * 64 + lane;
    const uint4* ap1 = Af + (size_t)((tap * MT_ + wvm * 2 + 1) * 2) * 64 + lane;
    bf16x8 ah0 = __builtin_bit_cast(bf16x8, ap0[0]);
    bf16x8 al0 = __builtin_bit_cast(bf16x8, ap0[64]);
    bf16x8 ah1 = __builtin_bit_cast(bf16x8, ap1[0]);
    bf16x8 al1 = __builtin_bit_cast(bf16x8, ap1[64]);

#pragma unroll
    for (int nt = 0; nt < 4; ++nt) {
      int pos = (wvn * 2 + (nt >> 1) + ky) * TPX + (nt & 1) * 16 + ln15 + kx;
      int sw  = pos & 3;
      uint4 hv = *(const uint4*)&tile[pos * ROWB4 + ((lg ^ sw) * 16)];
      bf16x8 bh = __builtin_bit_cast(bf16x8, hv);
      acc[0][nt] = __builtin_amdgcn_mfma_f32_16x16x32_bf16(ah0, bh, acc[0][nt], 0, 0, 0);
      acc[0][nt] = __builtin_amdgcn_mfma_f32_16x16x32_bf16(al0, bh, acc[0][nt], 0, 0, 0);
      acc[1][nt] = __builtin_amdgcn_mfma_f32_16x16x32_bf16(ah1, bh, acc[1][nt], 0, 0, 0);
      acc[1][nt] = __builtin_amdgcn_mfma_f32_16x16x32_bf16(al1, bh, acc[1][nt], 0, 0, 0);
    }
  }

  // NO barrier here: bounce is disjoint from tile; each wave proceeds into its
  // epilogue immediately, overlapping other waves' MFMA phase.

  // ---- lane-local LSTM epilogue; h -> bounce LDS as bf16-hi ----
#pragma unroll
  for (int mt = 0; mt < 2; ++mt) {
    int f = (wvm * 2 + mt) * 4 + lg;    // 0..23 (21..23 -> exact zero h)
    float4 bb = ((const float4*)bias4)[f];
#pragma unroll
    for (int nt = 0; nt < 4; ++nt) {
      int py = wvn * 2 + (nt >> 1);
      int px = (nt & 1) * 16 + ln15;
      int gy = by0 + py, gx = bx0 + px;
      if (gy < H_ && gx < W_) {
        int    pixL = py * TSX + px;
        size_t gpix = (size_t)gy * W_ + gx;
        float zi = acc[mt][nt][0] + bb.x;
        float zf = acc[mt][nt][1] + bb.y;
        float zc = acc[mt][nt][2] + bb.z;
        float zo = acc[mt][nt][3] + bb.w;
        float ig = hsig(zi);
        float fg = hsig(zf);
        float gg = fast_tanh(zc);
        float og = hsig(zo);
        float cp = cpre[mt][nt];
        float cn = fg * cp + ig * gg;
        float hn = og * fast_tanh(cn);
        if (f < F_ && !last) c_buf[((size_t)b * F_ + f) * HW_ + gpix] = cn;
        if (last) {
          if (f < F_)
            out[((size_t)(b * H_ + gy) * W_ + gx) * F_ + f] = hn * mask[gpix];
        } else {
          bh16[pixL * 24 + f] = bf16r(hn);
        }
      }
    }
  }

  if (last) return;
  __syncthreads();

  // ---- pack bounce -> g_out (coalesced 16B stores), 1 iter/thread ----
  for (int i = tid; i < 256 * 3; i += 768) {
    int g    = i >> 8;
    int pixL = i & 255;
    int py = pixL >> 5, px = pixL & 31;
    int gy = by0 + py, gx = bx0 + px;
    if (gy < H_ && gx < W_) {
      uint4 v = *(const uint4*)(bh16 + pixL * 24 + g * 8);
      g_out[(size_t)(b * 3 + g) * HW_ + (size_t)gy * W_ + gx] = v;
    }
  }
}

// ---------------- fallback path (round-2 proven structure, ~78 MB ws) ----------------
// Consumes the same Af (x_lo k-slots stage as zero; its ah*bl term recovers x_lo).
__global__ void __launch_bounds__(256, 3) step_kernel_f(
    const float* __restrict__ x,
    const uint4* __restrict__ Af,
    const float* __restrict__ bias4,
    const float* __restrict__ h_in,     // (B,F,HW) fp32
    float* __restrict__ h_out,          // (B,F,HW) fp32
    float* __restrict__ c_buf,
    const float* __restrict__ mask,
    float* __restrict__ out,
    int t, int first, int last) {
  __shared__ uint4 tileQ[NPOS * 8];
  unsigned char* tile = (unsigned char*)tileQ;

  int b   = blockIdx.z;
  int by0 = blockIdx.y * TSY;
  int bx0 = blockIdx.x * TSX;
  int tid = threadIdx.x;

  for (int i = tid; i < 32 * NPOS; i += 256) {
    int ci  = i / NPOS;
    int pos = i - ci * NPOS;
    int py = pos / TPX, px = pos - py * TPX;
    int gy = by0 - 1 + py, gx = bx0 - 1 + px;
    float v = 0.0f;
    if ((unsigned)gy < (unsigned)H_ && (unsigned)gx < (unsigned)W_) {
      if (ci < F_) {
        if (!first) v = h_in[(size_t)(b * F_ + ci) * HW_ + gy * W_ + gx];
      } else if (ci >= 24 && ci < 27) {
        v = x[(((size_t)(b * T_ + t) * H_ + gy) * W_ + gx) * C_ + (ci - 24)];
      }
    }
    unsigned short hb, lb;
    bsplit(v, hb, lb);
    int g  = ci >> 3, e = ci & 7, sw = pos & 7;
    *(unsigned short*)&tile[pos * ROWBF + (((g * 2 + 0) ^ sw) * 16) + e * 2] = hb;
    *(unsigned short*)&tile[pos * ROWBF + (((g * 2 + 1) ^ sw) * 16) + e * 2] = lb;
  }
  __syncthreads();

  int lane = tid & 63;
  int wv   = tid >> 6;
  int ln15 = lane & 15;
  int lg   = lane >> 4;

  f32x4 acc[MT_][4];
#pragma unroll
  for (int mt = 0; mt < MT_; ++mt)
#pragma unroll
    for (int nt = 0; nt < 4; ++nt)
      acc[mt][nt] = (f32x4){0.f, 0.f, 0.f, 0.f};

#pragma unroll 1
  for (int tap = 0; tap < NTAP; ++tap) {
    int ky = tap / 3;
    int kx = tap - 3 * ky;

    bf16x8 bh[4], bl[4];
#pragma unroll
    for (int nt = 0; nt < 4; ++nt) {
      int pos = (wv * 2 + (nt >> 1) + ky) * TPX + (nt & 1) * 16 + ln15 + kx;
      int sw  = pos & 7;
      uint4 hv = *(const uint4*)&tile[pos * ROWBF + (((lg * 2 + 0) ^ sw) * 16)];
      uint4 lv = *(const uint4*)&tile[pos * ROWBF + (((lg * 2 + 1) ^ sw) * 16)];
      bh[nt] = __builtin_bit_cast(bf16x8, hv);
      bl[nt] = __builtin_bit_cast(bf16x8, lv);
    }

#pragma unroll
    for (int mt = 0; mt < MT_; ++mt) {
      const uint4* ap = Af + (size_t)((tap * MT_ + mt) * 2) * 64 + lane;
      bf16x8 ah = __builtin_bit_cast(bf16x8, ap[0]);
      bf16x8 al = __builtin_bit_cast(bf16x8, ap[64]);
#pragma unroll
      for (int nt = 0; nt < 4; ++nt) {
        acc[mt][nt] = __builtin_amdgcn_mfma_f32_16x16x32_bf16(ah, bh[nt], acc[mt][nt], 0, 0, 0);
        acc[mt][nt] = __builtin_amdgcn_mfma_f32_16x16x32_bf16(ah, bl[nt], acc[mt][nt], 0, 0, 0);
        acc[mt][nt] = __builtin_amdgcn_mfma_f32_16x16x32_bf16(al, bh[nt], acc[mt][nt], 0, 0, 0);
      }
    }
  }

#pragma unroll
  for (int mt = 0; mt < MT_; ++mt) {
    int f = mt * 4 + lg;
    if (f < F_) {
      float4 bb = ((const float4*)bias4)[f];
#pragma unroll
      for (int nt = 0; nt < 4; ++nt) {
        int gy = by0 + wv * 2 + (nt >> 1);
        int gx = bx0 + (nt & 1) * 16 + ln15;
        if (gy < H_ && gx < W_) {
          size_t idx = ((size_t)b * F_ + f) * HW_ + (size_t)gy * W_ + gx;
          float zi = acc[mt][nt][0] + bb.x;
          float zf = acc[mt][nt][1] + bb.y;
          float zc = acc[mt][nt][2] + bb.z;
          float zo = acc[mt][nt][3] + bb.w;
          float ig = hsig(zi);
          float fg = hsig(zf);
          float gg = fast_tanh(zc);
          float og = hsig(zo);
          float cp = first ? 0.0f : c_buf[idx];
          float cn = fg * cp + ig * gg;
          float hn = og * fast_tanh(cn);
          c_buf[idx] = cn;
          if (!last) h_out[idx] = hn;
          else {
            out[((size_t)(b * H_ + gy) * W_ + gx) * F_ + f] =
                hn * mask[(size_t)gy * W_ + gx];
          }
        }
      }
    }
  }
}

extern "C" void kernel_launch(void* const* d_in, const int* in_sizes, int n_in,
                              void* d_out, int out_size, void* d_ws, size_t ws_size,
                              hipStream_t stream) {
  const float* x  = (const float*)d_in[0];
  const float* k  = (const float*)d_in[1];
  const float* rk = (const float*)d_in[2];
  const float* bs = (const float*)d_in[3];
  const float* mk = (const float*)d_in[4];
  float* outF = (float*)d_out;

  char* ws = (char*)d_ws;
  unsigned short* Af = (unsigned short*)ws;          // 110592 B
  float* bias4 = (float*)(ws + 110592);              // 384 B
  size_t off = (size_t)((110592 + 384 + 255) & ~255);
  size_t HWF = (size_t)B_ * H_ * W_ * F_;

  prep_kernel<<<dim3((NTAP * MT_ * 2 * 64 * 8 + 255) / 256), 256, 0, stream>>>(
      k, rk, bs, Af, bias4);

  dim3 grid((W_ + TSX - 1) / TSX, (H_ + TSY - 1) / TSY, B_);  // (6, 21, 16)

  size_t need_packed = off + (size_t)2 * GH_ * 16 + HWF * 4;  // ~84 MB

  if (ws_size >= need_packed) {
    // packed-h path: ghA/ghB = bf16-hi h planes, c fp32
    uint4* ghA = (uint4*)(ws + off);
    uint4* ghB = ghA + GH_;
    float* cB  = (float*)(ghB + GH_);
    for (int t = 0; t < T_; ++t) {
      const uint4* gin = (t & 1) ? ghB : ghA;
      uint4* gout      = (t & 1) ? ghA : ghB;
      step_kernel_p<<<grid, 768, 0, stream>>>(x, (const uint4*)Af, bias4, gin, gout,
                                              cB, mk, outF, t,
                                              (t == 0) ? 1 : 0, (t == T_ - 1) ? 1 : 0);
    }
  } else {
    // fallback (round-2 proven): fp32 h ping-pong via ws + outF, ~78.4 MB
    float* hA = (float*)(ws + off);
    float* cB = hA + HWF;
    for (int t = 0; t < T_; ++t) {
      const float* hi = (t & 1) ? hA : outF;
      float* ho       = (t & 1) ? outF : hA;
      step_kernel_f<<<grid, 256, 0, stream>>>(x, (const uint4*)Af, bias4, hi, ho,
                                              cB, mk, outF, t,
                                              (t == 0) ? 1 : 0, (t == T_ - 1) ? 1 : 0);
    }
  }
}